// Round 1
// baseline (1077.063 us; speedup 1.0000x reference)
//
#include <hip/hip_runtime.h>
#include <math.h>

#define N_NODES 100000
#define N_EDGES 1600000
#define IN_DIM  128
#define HID     64
#define NCOMM   32

// ---------- edge dtype detection (int64 vs int32, device-side, deterministic) ----------
__global__ void k_detect(const unsigned int* __restrict__ e, int* __restrict__ flag) {
  if (blockIdx.x == 0 && threadIdx.x == 0) {
    int allz = 1;
    for (int i = 0; i < 256; ++i) {
      if (e[2 * i + 1] != 0u) { allz = 0; break; }
    }
    *flag = allz;  // 1 => int64 layout, 0 => int32
  }
}

__device__ __forceinline__ int load_idx(const int* e32, long long pos, int is64) {
  if (is64) return (int)(((const long long*)e32)[pos]);
  return e32[pos];
}

// ---------- degree histogram over targets (self-loops handled analytically) ----------
__global__ __launch_bounds__(256) void k_hist(const int* __restrict__ e, int* __restrict__ deg,
                                              const int* __restrict__ flag) {
  int eid = blockIdx.x * 256 + threadIdx.x;
  if (eid >= N_EDGES) return;
  int is64 = *flag;
  int c = load_idx(e, (long long)N_EDGES + eid, is64);
  atomicAdd(&deg[c], 1);
}

// ---------- single-block exclusive scan -> CSR ptr, cursors, dinv ----------
__global__ __launch_bounds__(1024) void k_scan(const int* __restrict__ deg, int* __restrict__ ptr,
                                               int* __restrict__ cur, float* __restrict__ dinv) {
  __shared__ int sm[1024];
  const int tid = threadIdx.x;
  const int chunk = (N_NODES + 1023) / 1024;
  int start = tid * chunk;
  int end = start + chunk; if (end > N_NODES) end = N_NODES;
  int s = 0;
  for (int i = start; i < end; ++i) s += deg[i];
  sm[tid] = s;
  __syncthreads();
  for (int off = 1; off < 1024; off <<= 1) {
    int t = (tid >= off) ? sm[tid - off] : 0;
    __syncthreads();
    sm[tid] += t;
    __syncthreads();
  }
  int run = sm[tid] - s;  // exclusive prefix of this thread's chunk
  for (int i = start; i < end; ++i) {
    ptr[i] = run;
    cur[i] = run;
    dinv[i] = rsqrtf((float)deg[i] + 1.0f);  // +1 = self loop; always > 0
    run += deg[i];
  }
  if (tid == 0) ptr[N_NODES] = sm[1023];
}

// ---------- counting-sort edges by target ----------
__global__ __launch_bounds__(256) void k_sort(const int* __restrict__ e, int* __restrict__ cur,
                                              int* __restrict__ srow, const int* __restrict__ flag) {
  int eid = blockIdx.x * 256 + threadIdx.x;
  if (eid >= N_EDGES) return;
  int is64 = *flag;
  int r = load_idx(e, eid, is64);
  int c = load_idx(e, (long long)N_EDGES + eid, is64);
  int pos = atomicAdd(&cur[c], 1);
  srow[pos] = r;
}

// ---------- dense GEMM: Y[n,M] = X[n,K] @ W[K,M]; optional bias+sigmoid epilogue ----------
template<int K, int M, bool FINAL>
__global__ __launch_bounds__(256) void k_gemm(const float* __restrict__ X, const float* __restrict__ W,
                                              float* __restrict__ Y, const float* __restrict__ bias) {
  constexpr int CG  = M / 4;     // float4 column-groups per row
  constexpr int NPB = 256 / CG;  // nodes per block iteration
  __shared__ float4 w4[K * CG];
  const float4* Wv = (const float4*)W;
  for (int i = threadIdx.x; i < K * CG; i += 256) w4[i] = Wv[i];
  __syncthreads();
  const int cg = threadIdx.x % CG;
  const int ns = threadIdx.x / CG;
  for (int node = blockIdx.x * NPB + ns; node < N_NODES; node += gridDim.x * NPB) {
    const float4* xr = (const float4*)(X + (size_t)node * K);
    float ax = 0.f, ay = 0.f, az = 0.f, aw = 0.f;
    #pragma unroll
    for (int k4 = 0; k4 < K / 4; ++k4) {
      float4 xv = xr[k4];
      float4 w0 = w4[(k4 * 4 + 0) * CG + cg];
      float4 w1 = w4[(k4 * 4 + 1) * CG + cg];
      float4 w2 = w4[(k4 * 4 + 2) * CG + cg];
      float4 w3 = w4[(k4 * 4 + 3) * CG + cg];
      ax += xv.x * w0.x + xv.y * w1.x + xv.z * w2.x + xv.w * w3.x;
      ay += xv.x * w0.y + xv.y * w1.y + xv.z * w2.y + xv.w * w3.y;
      az += xv.x * w0.z + xv.y * w1.z + xv.z * w2.z + xv.w * w3.z;
      aw += xv.x * w0.w + xv.y * w1.w + xv.z * w2.w + xv.w * w3.w;
    }
    float4 o;
    if (FINAL) {
      float4 bv = ((const float4*)bias)[cg];
      o.x = 1.f / (1.f + __expf(-(ax + bv.x)));
      o.y = 1.f / (1.f + __expf(-(ay + bv.y)));
      o.z = 1.f / (1.f + __expf(-(az + bv.z)));
      o.w = 1.f / (1.f + __expf(-(aw + bv.w)));
    } else {
      o.x = ax; o.y = ay; o.z = az; o.w = aw;
    }
    ((float4*)(Y + (size_t)node * M))[cg] = o;
  }
}

// ---------- pull aggregation: O[c] = relu( sum_{e:col=c} H[row_e]*dinv[r]*dinv[c] + H[c]*dinv[c]^2 + b ) ----------
__global__ __launch_bounds__(256) void k_agg(const float* __restrict__ H, float* __restrict__ O,
                                             const int* __restrict__ ptr, const int* __restrict__ srow,
                                             const float* __restrict__ dinv, const float* __restrict__ bias) {
  int wid  = (blockIdx.x * 256 + threadIdx.x) >> 6;  // node (one wave per node)
  int lane = threadIdx.x & 63;                       // feature
  if (wid >= N_NODES) return;
  float di  = dinv[wid];
  float acc = H[(size_t)wid * HID + lane] * di * di;  // self loop
  int s = ptr[wid], e = ptr[wid + 1];
  for (int j = s; j < e; ++j) {
    int r = srow[j];
    acc += H[(size_t)r * HID + lane] * (dinv[r] * di);
  }
  O[(size_t)wid * HID + lane] = fmaxf(acc + bias[lane], 0.0f);
}

extern "C" void kernel_launch(void* const* d_in, const int* in_sizes, int n_in,
                              void* d_out, int out_size, void* d_ws, size_t ws_size,
                              hipStream_t stream) {
  const float* x   = (const float*)d_in[0];
  const int*   e   = (const int*)d_in[1];
  const float* W1  = (const float*)d_in[2];
  const float* b1  = (const float*)d_in[3];
  const float* W2  = (const float*)d_in[4];
  const float* b2  = (const float*)d_in[5];
  const float* Wfc = (const float*)d_in[6];
  const float* bfc = (const float*)d_in[7];
  float* out = (float*)d_out;

  // workspace layout (bytes)
  char* ws = (char*)d_ws;
  float* bufA = (float*)(ws);               // N*64 f32 = 25,600,000
  float* bufB = (float*)(ws + 25600000);    // N*64 f32
  int*   deg  = (int*)  (ws + 51200000);    // N i32
  float* dinv = (float*)(ws + 51600000);    // N f32
  int*   ptr  = (int*)  (ws + 52000000);    // (N+1) i32
  int*   cur  = (int*)  (ws + 52400128);    // N i32
  int*   srow = (int*)  (ws + 52800128);    // E i32
  int*   flag = (int*)  (ws + 59200128);    // 1 i32

  hipMemsetAsync(deg, 0, N_NODES * sizeof(int), stream);
  k_detect<<<1, 64, 0, stream>>>((const unsigned int*)e, flag);
  k_hist<<<N_EDGES / 256, 256, 0, stream>>>(e, deg, flag);
  k_scan<<<1, 1024, 0, stream>>>(deg, ptr, cur, dinv);
  k_sort<<<N_EDGES / 256, 256, 0, stream>>>(e, cur, srow, flag);

  k_gemm<IN_DIM, HID, false><<<2048, 256, 0, stream>>>(x, W1, bufA, nullptr);
  k_agg<<<N_NODES * HID / 256, 256, 0, stream>>>(bufA, bufB, ptr, srow, dinv, b1);
  k_gemm<HID, HID, false><<<2048, 256, 0, stream>>>(bufB, W2, bufA, nullptr);
  k_agg<<<N_NODES * HID / 256, 256, 0, stream>>>(bufA, bufB, ptr, srow, dinv, b2);
  k_gemm<HID, NCOMM, true><<<2048, 256, 0, stream>>>(bufB, Wfc, out, bfc);
}

// Round 2
// 506.142 us; speedup vs baseline: 2.1280x; 2.1280x over previous
//
#include <hip/hip_runtime.h>
#include <math.h>

#define N_NODES 100000
#define N_EDGES 1600000
#define IN_DIM  128
#define HID     64
#define NCOMM   32
#define NBLK_SCAN 98   // ceil(100000/1024)

// ---------- edge dtype detection (int64 vs int32), parallel, deterministic ----------
__global__ void k_detect(const unsigned int* __restrict__ e, int* __restrict__ flag) {
  int lane = threadIdx.x;  // 64 lanes
  unsigned v = 0;
  #pragma unroll
  for (int i = 0; i < 4; ++i) v |= e[2 * (lane * 4 + i) + 1];
  unsigned long long nz = __ballot(v != 0u);
  if (lane == 0) *flag = (nz == 0ull) ? 1 : 0;  // 1 => int64 layout
}

__device__ __forceinline__ int load_idx(const int* e32, long long pos, int is64) {
  if (is64) return (int)(((const long long*)e32)[pos]);
  return e32[pos];
}

// ---------- degree histogram over targets ----------
__global__ __launch_bounds__(256) void k_hist(const int* __restrict__ e, int* __restrict__ deg,
                                              const int* __restrict__ flag) {
  int eid = blockIdx.x * 256 + threadIdx.x;
  if (eid >= N_EDGES) return;
  int is64 = *flag;
  int c = load_idx(e, (long long)N_EDGES + eid, is64);
  atomicAdd(&deg[c], 1);
}

// ---------- two-level scan: A (local scan + partials), B (scan partials), C (add-back) ----------
__global__ __launch_bounds__(1024) void k_scan_a(const int* __restrict__ deg, int* __restrict__ excl,
                                                 float* __restrict__ dinv, int* __restrict__ part) {
  __shared__ int sm[1024];
  int t = threadIdx.x;
  int i = blockIdx.x * 1024 + t;
  int d = (i < N_NODES) ? deg[i] : 0;
  sm[t] = d;
  __syncthreads();
  for (int off = 1; off < 1024; off <<= 1) {
    int u = (t >= off) ? sm[t - off] : 0;
    __syncthreads();
    sm[t] += u;
    __syncthreads();
  }
  if (i < N_NODES) {
    excl[i] = sm[t] - d;
    dinv[i] = rsqrtf((float)d + 1.0f);  // +1 = self loop; always > 0
  }
  if (t == 1023) part[blockIdx.x] = sm[1023];
}

__global__ __launch_bounds__(128) void k_scan_b(int* __restrict__ part) {
  __shared__ int sm[128];
  int t = threadIdx.x;
  int v = (t < NBLK_SCAN) ? part[t] : 0;
  sm[t] = v;
  __syncthreads();
  for (int off = 1; off < 128; off <<= 1) {
    int u = (t >= off) ? sm[t - off] : 0;
    __syncthreads();
    sm[t] += u;
    __syncthreads();
  }
  if (t < NBLK_SCAN) part[t] = sm[t] - v;  // exclusive
}

__global__ __launch_bounds__(1024) void k_scan_c(const int* __restrict__ excl, const int* __restrict__ part,
                                                 int* __restrict__ ptr, int* __restrict__ cur) {
  int i = blockIdx.x * 1024 + threadIdx.x;
  if (i < N_NODES) {
    int p = excl[i] + part[blockIdx.x];
    ptr[i] = p;
    cur[i] = p;
  }
  if (i == 0) ptr[N_NODES] = N_EDGES;
}

// ---------- counting-sort edges by target ----------
__global__ __launch_bounds__(256) void k_sort(const int* __restrict__ e, int* __restrict__ cur,
                                              int* __restrict__ srow, const int* __restrict__ flag) {
  int eid = blockIdx.x * 256 + threadIdx.x;
  if (eid >= N_EDGES) return;
  int is64 = *flag;
  int r = load_idx(e, eid, is64);
  int c = load_idx(e, (long long)N_EDGES + eid, is64);
  int pos = atomicAdd(&cur[c], 1);
  srow[pos] = r;
}

// ---------- dense GEMM: Y[n,M] = X[n,K] @ W[K,M]; each thread: 4 nodes x 4 cols ----------
__device__ __forceinline__ float4 epil(float4 a, float4 bv, bool fin) {
  if (fin) {
    a.x = 1.f / (1.f + __expf(-(a.x + bv.x)));
    a.y = 1.f / (1.f + __expf(-(a.y + bv.y)));
    a.z = 1.f / (1.f + __expf(-(a.z + bv.z)));
    a.w = 1.f / (1.f + __expf(-(a.w + bv.w)));
  }
  return a;
}

#define DOT4(acc, xv)                                          \
  acc.x += xv.x * w0.x + xv.y * w1.x + xv.z * w2.x + xv.w * w3.x; \
  acc.y += xv.x * w0.y + xv.y * w1.y + xv.z * w2.y + xv.w * w3.y; \
  acc.z += xv.x * w0.z + xv.y * w1.z + xv.z * w2.z + xv.w * w3.z; \
  acc.w += xv.x * w0.w + xv.y * w1.w + xv.z * w2.w + xv.w * w3.w;

template<int K, int M, bool FINAL>
__global__ __launch_bounds__(256) void k_gemm(const float* __restrict__ X, const float* __restrict__ W,
                                              float* __restrict__ Y, const float* __restrict__ bias) {
  constexpr int CG  = M / 4;      // float4 col-groups: 16 (M=64) or 8 (M=32)
  constexpr int NG  = 256 / CG;   // node-groups per block
  constexpr int NPT = 4;          // nodes per thread
  constexpr int NPB = NG * NPT;   // nodes per block: 64 or 128
  __shared__ float4 w4[K * CG];
  const float4* Wv = (const float4*)W;
  for (int i = threadIdx.x; i < K * CG; i += 256) w4[i] = Wv[i];
  __syncthreads();
  const int cg = threadIdx.x % CG;
  const int ng = threadIdx.x / CG;
  const int base = blockIdx.x * NPB + ng * NPT;
  if (base >= N_NODES) return;
  float4 bv = {0, 0, 0, 0};
  if (FINAL) bv = ((const float4*)bias)[cg];

  if (base + NPT <= N_NODES) {
    const float4* xr = (const float4*)(X + (size_t)base * K);
    float4 a0 = {0,0,0,0}, a1 = {0,0,0,0}, a2 = {0,0,0,0}, a3 = {0,0,0,0};
    #pragma unroll 2
    for (int k4 = 0; k4 < K / 4; ++k4) {
      float4 w0 = w4[(k4 * 4 + 0) * CG + cg];
      float4 w1 = w4[(k4 * 4 + 1) * CG + cg];
      float4 w2 = w4[(k4 * 4 + 2) * CG + cg];
      float4 w3 = w4[(k4 * 4 + 3) * CG + cg];
      float4 x0 = xr[0 * (K / 4) + k4];
      float4 x1 = xr[1 * (K / 4) + k4];
      float4 x2 = xr[2 * (K / 4) + k4];
      float4 x3 = xr[3 * (K / 4) + k4];
      DOT4(a0, x0);
      DOT4(a1, x1);
      DOT4(a2, x2);
      DOT4(a3, x3);
    }
    ((float4*)(Y + (size_t)(base + 0) * M))[cg] = epil(a0, bv, FINAL);
    ((float4*)(Y + (size_t)(base + 1) * M))[cg] = epil(a1, bv, FINAL);
    ((float4*)(Y + (size_t)(base + 2) * M))[cg] = epil(a2, bv, FINAL);
    ((float4*)(Y + (size_t)(base + 3) * M))[cg] = epil(a3, bv, FINAL);
  } else {
    // tail block: per-node simple path
    for (int n = 0; n < N_NODES - base; ++n) {
      const float4* xr = (const float4*)(X + (size_t)(base + n) * K);
      float4 a = {0, 0, 0, 0};
      for (int k4 = 0; k4 < K / 4; ++k4) {
        float4 w0 = w4[(k4 * 4 + 0) * CG + cg];
        float4 w1 = w4[(k4 * 4 + 1) * CG + cg];
        float4 w2 = w4[(k4 * 4 + 2) * CG + cg];
        float4 w3 = w4[(k4 * 4 + 3) * CG + cg];
        float4 xv = xr[k4];
        DOT4(a, xv);
      }
      ((float4*)(Y + (size_t)(base + n) * M))[cg] = epil(a, bv, FINAL);
    }
  }
}

// ---------- pull aggregation: O = relu( sum_in H[r]*dinv[r]*dinv[c] + H[c]*dinv[c]^2 + b ) ----------
__global__ __launch_bounds__(256) void k_agg(const float* __restrict__ H, float* __restrict__ O,
                                             const int* __restrict__ ptr, const int* __restrict__ srow,
                                             const float* __restrict__ dinv, const float* __restrict__ bias) {
  int wid  = (blockIdx.x * 256 + threadIdx.x) >> 6;  // node (one wave per node)
  int lane = threadIdx.x & 63;                       // feature
  if (wid >= N_NODES) return;
  float di  = dinv[wid];
  float acc = H[(size_t)wid * HID + lane] * di * di;  // self loop
  int s = ptr[wid], e = ptr[wid + 1];
  int j = s;
  for (; j + 1 < e; j += 2) {
    int r0 = srow[j];
    int r1 = srow[j + 1];
    float n0 = dinv[r0] * di;
    float n1 = dinv[r1] * di;
    float h0 = H[(size_t)r0 * HID + lane];
    float h1 = H[(size_t)r1 * HID + lane];
    acc += h0 * n0;
    acc += h1 * n1;
  }
  if (j < e) {
    int r = srow[j];
    acc += H[(size_t)r * HID + lane] * (dinv[r] * di);
  }
  O[(size_t)wid * HID + lane] = fmaxf(acc + bias[lane], 0.0f);
}

extern "C" void kernel_launch(void* const* d_in, const int* in_sizes, int n_in,
                              void* d_out, int out_size, void* d_ws, size_t ws_size,
                              hipStream_t stream) {
  const float* x   = (const float*)d_in[0];
  const int*   e   = (const int*)d_in[1];
  const float* W1  = (const float*)d_in[2];
  const float* b1  = (const float*)d_in[3];
  const float* W2  = (const float*)d_in[4];
  const float* b2  = (const float*)d_in[5];
  const float* Wfc = (const float*)d_in[6];
  const float* bfc = (const float*)d_in[7];
  float* out = (float*)d_out;

  // workspace layout (bytes)
  char* ws = (char*)d_ws;
  float* bufA = (float*)(ws);               // N*64 f32
  float* bufB = (float*)(ws + 25600000);    // N*64 f32
  int*   deg  = (int*)  (ws + 51200000);    // N i32
  float* dinv = (float*)(ws + 51600000);    // N f32
  int*   ptr  = (int*)  (ws + 52000000);    // (N+1) i32
  int*   cur  = (int*)  (ws + 52400128);    // N i32 (also holds local-excl-scan temp)
  int*   srow = (int*)  (ws + 52800128);    // E i32
  int*   flag = (int*)  (ws + 59200128);    // 1 i32
  int*   part = (int*)  (ws + 59200192);    // NBLK_SCAN i32

  hipMemsetAsync(deg, 0, N_NODES * sizeof(int), stream);
  k_detect<<<1, 64, 0, stream>>>((const unsigned int*)e, flag);
  k_hist<<<N_EDGES / 256, 256, 0, stream>>>(e, deg, flag);
  k_scan_a<<<NBLK_SCAN, 1024, 0, stream>>>(deg, cur, dinv, part);
  k_scan_b<<<1, 128, 0, stream>>>(part);
  k_scan_c<<<NBLK_SCAN, 1024, 0, stream>>>(cur, part, ptr, cur);
  k_sort<<<N_EDGES / 256, 256, 0, stream>>>(e, cur, srow, flag);

  k_gemm<IN_DIM, HID, false><<<(N_NODES + 63) / 64, 256, 0, stream>>>(x, W1, bufA, nullptr);
  k_agg<<<N_NODES * HID / 256, 256, 0, stream>>>(bufA, bufB, ptr, srow, dinv, b1);
  k_gemm<HID, HID, false><<<(N_NODES + 63) / 64, 256, 0, stream>>>(bufB, W2, bufA, nullptr);
  k_agg<<<N_NODES * HID / 256, 256, 0, stream>>>(bufA, bufB, ptr, srow, dinv, b2);
  k_gemm<HID, NCOMM, true><<<(N_NODES + 127) / 128, 256, 0, stream>>>(bufB, Wfc, out, bfc);
}

// Round 3
// 373.203 us; speedup vs baseline: 2.8860x; 1.3562x over previous
//
#include <hip/hip_runtime.h>
#include <math.h>

#define N_NODES 100000
#define N_EDGES 1600000
#define IN_DIM  128
#define HID     64
#define NCOMM   32
#define NBLK_SCAN 98    // ceil(100000/1024)
#define NB        391   // ceil(100000/256) coarse buckets
#define BSHIFT    8     // 256 nodes per bucket
#define EPB       4096  // edges per block in binning kernels
#define NBIN_BLK  391   // ceil(1600000/4096)

// ---------- edge dtype detection (int64 vs int32), parallel, deterministic ----------
__global__ void k_detect(const unsigned int* __restrict__ e, int* __restrict__ flag) {
  int lane = threadIdx.x;  // 64 lanes
  unsigned v = 0;
  #pragma unroll
  for (int i = 0; i < 4; ++i) v |= e[2 * (lane * 4 + i) + 1];
  unsigned long long nz = __ballot(v != 0u);
  if (lane == 0) *flag = (nz == 0ull) ? 1 : 0;  // 1 => int64 layout
}

__device__ __forceinline__ int load_idx(const int* e32, long long pos, int is64) {
  if (is64) return (int)(((const long long*)e32)[pos]);
  return e32[pos];
}

// ---------- coarse bucket histogram (LDS counters, few global atomics) ----------
__global__ __launch_bounds__(256) void k_bhist(const int* __restrict__ e, int* __restrict__ bcnt,
                                               const int* __restrict__ flag) {
  __shared__ int cnt[NB];
  for (int i = threadIdx.x; i < NB; i += 256) cnt[i] = 0;
  __syncthreads();
  int is64 = *flag;
  long long base = (long long)blockIdx.x * EPB;
  #pragma unroll
  for (int j = 0; j < EPB / 256; ++j) {
    long long eid = base + j * 256 + threadIdx.x;
    if (eid < N_EDGES) {
      int c = load_idx(e, (long long)N_EDGES + eid, is64);
      atomicAdd(&cnt[c >> BSHIFT], 1);
    }
  }
  __syncthreads();
  for (int b = threadIdx.x; b < NB; b += 256)
    if (cnt[b]) atomicAdd(&bcnt[b], cnt[b]);
}

// ---------- scan coarse buckets -> bptr, bcur ----------
__global__ __launch_bounds__(512) void k_bscan(const int* __restrict__ bcnt, int* __restrict__ bptr,
                                               int* __restrict__ bcur) {
  __shared__ int sm[512];
  int t = threadIdx.x;
  int v = (t < NB) ? bcnt[t] : 0;
  sm[t] = v;
  __syncthreads();
  for (int off = 1; off < 512; off <<= 1) {
    int u = (t >= off) ? sm[t - off] : 0;
    __syncthreads();
    sm[t] += u;
    __syncthreads();
  }
  if (t < NB) {
    int ex = sm[t] - v;
    bptr[t] = ex;
    bcur[t] = ex;
  }
  if (t == 0) bptr[NB] = N_EDGES;
}

// ---------- bin edges into coarse buckets as packed (r,c) ----------
__global__ __launch_bounds__(256) void k_bin(const int* __restrict__ e, int* __restrict__ bcur,
                                             uint2* __restrict__ ebuf, const int* __restrict__ flag) {
  __shared__ int cnt[NB];
  __shared__ int base[NB];
  for (int i = threadIdx.x; i < NB; i += 256) cnt[i] = 0;
  __syncthreads();
  int is64 = *flag;
  long long eb = (long long)blockIdx.x * EPB;
  int rr[EPB / 256], cc[EPB / 256], lr[EPB / 256];
  #pragma unroll
  for (int j = 0; j < EPB / 256; ++j) {
    long long eid = eb + j * 256 + threadIdx.x;
    if (eid < N_EDGES) {
      rr[j] = load_idx(e, eid, is64);
      cc[j] = load_idx(e, (long long)N_EDGES + eid, is64);
      lr[j] = atomicAdd(&cnt[cc[j] >> BSHIFT], 1);
    }
  }
  __syncthreads();
  for (int b = threadIdx.x; b < NB; b += 256)
    base[b] = cnt[b] ? atomicAdd(&bcur[b], cnt[b]) : 0;
  __syncthreads();
  #pragma unroll
  for (int j = 0; j < EPB / 256; ++j) {
    long long eid = eb + j * 256 + threadIdx.x;
    if (eid < N_EDGES) {
      int pos = base[cc[j] >> BSHIFT] + lr[j];
      ebuf[pos] = make_uint2((unsigned)rr[j], (unsigned)cc[j]);
    }
  }
}

// ---------- per-bucket degree histogram (LDS, no global atomics) + dinv ----------
__global__ __launch_bounds__(256) void k_deg(const uint2* __restrict__ ebuf, const int* __restrict__ bptr,
                                             int* __restrict__ deg, float* __restrict__ dinv) {
  __shared__ int cnt[256];
  int b = blockIdx.x;
  int c0 = b << BSHIFT;
  cnt[threadIdx.x] = 0;
  __syncthreads();
  int s = bptr[b], epos = bptr[b + 1];
  for (int i = s + threadIdx.x; i < epos; i += 256)
    atomicAdd(&cnt[(int)ebuf[i].y - c0], 1);
  __syncthreads();
  int node = c0 + threadIdx.x;
  if (node < N_NODES) {
    int d = cnt[threadIdx.x];
    deg[node] = d;
    dinv[node] = rsqrtf((float)d + 1.0f);  // +1 = self loop; always > 0
  }
}

// ---------- two-level scan of deg -> ptr ----------
__global__ __launch_bounds__(1024) void k_scan_a(const int* __restrict__ deg, int* __restrict__ excl,
                                                 int* __restrict__ part) {
  __shared__ int sm[1024];
  int t = threadIdx.x;
  int i = blockIdx.x * 1024 + t;
  int d = (i < N_NODES) ? deg[i] : 0;
  sm[t] = d;
  __syncthreads();
  for (int off = 1; off < 1024; off <<= 1) {
    int u = (t >= off) ? sm[t - off] : 0;
    __syncthreads();
    sm[t] += u;
    __syncthreads();
  }
  if (i < N_NODES) excl[i] = sm[t] - d;
  if (t == 1023) part[blockIdx.x] = sm[1023];
}

__global__ __launch_bounds__(128) void k_scan_b(int* __restrict__ part) {
  __shared__ int sm[128];
  int t = threadIdx.x;
  int v = (t < NBLK_SCAN) ? part[t] : 0;
  sm[t] = v;
  __syncthreads();
  for (int off = 1; off < 128; off <<= 1) {
    int u = (t >= off) ? sm[t - off] : 0;
    __syncthreads();
    sm[t] += u;
    __syncthreads();
  }
  if (t < NBLK_SCAN) part[t] = sm[t] - v;  // exclusive
}

__global__ __launch_bounds__(1024) void k_scan_c(const int* __restrict__ excl, const int* __restrict__ part,
                                                 int* __restrict__ ptr) {
  int i = blockIdx.x * 1024 + threadIdx.x;
  if (i < N_NODES) ptr[i] = excl[i] + part[blockIdx.x];
  if (i == 0) ptr[N_NODES] = N_EDGES;
}

// ---------- fine sort within bucket: LDS cursors, L2-local scatter ----------
__global__ __launch_bounds__(1024) void k_fsort(const uint2* __restrict__ ebuf, const int* __restrict__ bptr,
                                                const int* __restrict__ ptr, int* __restrict__ srow) {
  __shared__ int cur[256];
  int b = blockIdx.x;
  int c0 = b << BSHIFT;
  if (threadIdx.x < 256) {
    int node = c0 + threadIdx.x;
    cur[threadIdx.x] = (node < N_NODES) ? ptr[node] : 0;
  }
  __syncthreads();
  int s = bptr[b], epos = bptr[b + 1];
  for (int i = s + (int)threadIdx.x; i < epos; i += 1024) {
    uint2 ed = ebuf[i];
    int pos = atomicAdd(&cur[(int)ed.y - c0], 1);
    srow[pos] = (int)ed.x;
  }
}

// ---------- dense GEMM: Y[n,M] = X[n,K] @ W[K,M]; each thread: 4 nodes x 4 cols ----------
__device__ __forceinline__ float4 epil(float4 a, float4 bv, bool fin) {
  if (fin) {
    a.x = 1.f / (1.f + __expf(-(a.x + bv.x)));
    a.y = 1.f / (1.f + __expf(-(a.y + bv.y)));
    a.z = 1.f / (1.f + __expf(-(a.z + bv.z)));
    a.w = 1.f / (1.f + __expf(-(a.w + bv.w)));
  }
  return a;
}

#define DOT4(acc, xv)                                          \
  acc.x += xv.x * w0.x + xv.y * w1.x + xv.z * w2.x + xv.w * w3.x; \
  acc.y += xv.x * w0.y + xv.y * w1.y + xv.z * w2.y + xv.w * w3.y; \
  acc.z += xv.x * w0.z + xv.y * w1.z + xv.z * w2.z + xv.w * w3.z; \
  acc.w += xv.x * w0.w + xv.y * w1.w + xv.z * w2.w + xv.w * w3.w;

template<int K, int M, bool FINAL>
__global__ __launch_bounds__(256) void k_gemm(const float* __restrict__ X, const float* __restrict__ W,
                                              float* __restrict__ Y, const float* __restrict__ bias) {
  constexpr int CG  = M / 4;      // float4 col-groups: 16 (M=64) or 8 (M=32)
  constexpr int NG  = 256 / CG;   // node-groups per block
  constexpr int NPT = 4;          // nodes per thread
  constexpr int NPB = NG * NPT;   // nodes per block: 64 or 128
  __shared__ float4 w4[K * CG];
  const float4* Wv = (const float4*)W;
  for (int i = threadIdx.x; i < K * CG; i += 256) w4[i] = Wv[i];
  __syncthreads();
  const int cg = threadIdx.x % CG;
  const int ng = threadIdx.x / CG;
  const int base = blockIdx.x * NPB + ng * NPT;
  if (base >= N_NODES) return;
  float4 bv = {0, 0, 0, 0};
  if (FINAL) bv = ((const float4*)bias)[cg];

  if (base + NPT <= N_NODES) {
    const float4* xr = (const float4*)(X + (size_t)base * K);
    float4 a0 = {0,0,0,0}, a1 = {0,0,0,0}, a2 = {0,0,0,0}, a3 = {0,0,0,0};
    #pragma unroll 2
    for (int k4 = 0; k4 < K / 4; ++k4) {
      float4 w0 = w4[(k4 * 4 + 0) * CG + cg];
      float4 w1 = w4[(k4 * 4 + 1) * CG + cg];
      float4 w2 = w4[(k4 * 4 + 2) * CG + cg];
      float4 w3 = w4[(k4 * 4 + 3) * CG + cg];
      float4 x0 = xr[0 * (K / 4) + k4];
      float4 x1 = xr[1 * (K / 4) + k4];
      float4 x2 = xr[2 * (K / 4) + k4];
      float4 x3 = xr[3 * (K / 4) + k4];
      DOT4(a0, x0);
      DOT4(a1, x1);
      DOT4(a2, x2);
      DOT4(a3, x3);
    }
    ((float4*)(Y + (size_t)(base + 0) * M))[cg] = epil(a0, bv, FINAL);
    ((float4*)(Y + (size_t)(base + 1) * M))[cg] = epil(a1, bv, FINAL);
    ((float4*)(Y + (size_t)(base + 2) * M))[cg] = epil(a2, bv, FINAL);
    ((float4*)(Y + (size_t)(base + 3) * M))[cg] = epil(a3, bv, FINAL);
  } else {
    // tail block: per-node simple path
    for (int n = 0; n < N_NODES - base; ++n) {
      const float4* xr = (const float4*)(X + (size_t)(base + n) * K);
      float4 a = {0, 0, 0, 0};
      for (int k4 = 0; k4 < K / 4; ++k4) {
        float4 w0 = w4[(k4 * 4 + 0) * CG + cg];
        float4 w1 = w4[(k4 * 4 + 1) * CG + cg];
        float4 w2 = w4[(k4 * 4 + 2) * CG + cg];
        float4 w3 = w4[(k4 * 4 + 3) * CG + cg];
        float4 xv = xr[k4];
        DOT4(a, xv);
      }
      ((float4*)(Y + (size_t)(base + n) * M))[cg] = epil(a, bv, FINAL);
    }
  }
}

// ---------- pull aggregation: O = relu( sum_in H[r]*dinv[r]*dinv[c] + H[c]*dinv[c]^2 + b ) ----------
__global__ __launch_bounds__(256) void k_agg(const float* __restrict__ H, float* __restrict__ O,
                                             const int* __restrict__ ptr, const int* __restrict__ srow,
                                             const float* __restrict__ dinv, const float* __restrict__ bias) {
  int wid  = (blockIdx.x * 256 + threadIdx.x) >> 6;  // node (one wave per node)
  int lane = threadIdx.x & 63;                       // feature
  if (wid >= N_NODES) return;
  float di  = dinv[wid];
  float acc = H[(size_t)wid * HID + lane] * di * di;  // self loop
  int s = ptr[wid], e = ptr[wid + 1];
  int j = s;
  for (; j + 1 < e; j += 2) {
    int r0 = srow[j];
    int r1 = srow[j + 1];
    float n0 = dinv[r0] * di;
    float n1 = dinv[r1] * di;
    float h0 = H[(size_t)r0 * HID + lane];
    float h1 = H[(size_t)r1 * HID + lane];
    acc += h0 * n0;
    acc += h1 * n1;
  }
  if (j < e) {
    int r = srow[j];
    acc += H[(size_t)r * HID + lane] * (dinv[r] * di);
  }
  O[(size_t)wid * HID + lane] = fmaxf(acc + bias[lane], 0.0f);
}

extern "C" void kernel_launch(void* const* d_in, const int* in_sizes, int n_in,
                              void* d_out, int out_size, void* d_ws, size_t ws_size,
                              hipStream_t stream) {
  const float* x   = (const float*)d_in[0];
  const int*   e   = (const int*)d_in[1];
  const float* W1  = (const float*)d_in[2];
  const float* b1  = (const float*)d_in[3];
  const float* W2  = (const float*)d_in[4];
  const float* b2  = (const float*)d_in[5];
  const float* Wfc = (const float*)d_in[6];
  const float* bfc = (const float*)d_in[7];
  float* out = (float*)d_out;

  // workspace layout (bytes)
  char* ws = (char*)d_ws;
  float* bufA = (float*)(ws);               // N*64 f32
  float* bufB = (float*)(ws + 25600000);    // N*64 f32 (ALIASED: ebuf lives here pre-agg)
  uint2* ebuf = (uint2*)(ws + 25600000);    // E uint2 = 12.8 MB, dead after k_fsort
  int*   deg  = (int*)  (ws + 51200000);    // N i32
  float* dinv = (float*)(ws + 51600000);    // N f32
  int*   ptr  = (int*)  (ws + 52000000);    // (N+1) i32
  int*   excl = (int*)  (ws + 52400128);    // N i32 scan temp
  int*   srow = (int*)  (ws + 52800128);    // E i32
  int*   flag = (int*)  (ws + 59200128);    // 1 i32
  int*   part = (int*)  (ws + 59200192);    // NBLK_SCAN i32
  int*   bcnt = (int*)  (ws + 59200704);    // NB i32
  int*   bptr = (int*)  (ws + 59202368);    // NB+1 i32
  int*   bcur = (int*)  (ws + 59204096);    // NB i32

  hipMemsetAsync(bcnt, 0, NB * sizeof(int), stream);
  k_detect<<<1, 64, 0, stream>>>((const unsigned int*)e, flag);
  k_bhist<<<NBIN_BLK, 256, 0, stream>>>(e, bcnt, flag);
  k_bscan<<<1, 512, 0, stream>>>(bcnt, bptr, bcur);
  k_bin<<<NBIN_BLK, 256, 0, stream>>>(e, bcur, ebuf, flag);
  k_deg<<<NB, 256, 0, stream>>>(ebuf, bptr, deg, dinv);
  k_scan_a<<<NBLK_SCAN, 1024, 0, stream>>>(deg, excl, part);
  k_scan_b<<<1, 128, 0, stream>>>(part);
  k_scan_c<<<NBLK_SCAN, 1024, 0, stream>>>(excl, part, ptr);
  k_fsort<<<NB, 1024, 0, stream>>>(ebuf, bptr, ptr, srow);

  k_gemm<IN_DIM, HID, false><<<(N_NODES + 63) / 64, 256, 0, stream>>>(x, W1, bufA, nullptr);
  k_agg<<<N_NODES * HID / 256, 256, 0, stream>>>(bufA, bufB, ptr, srow, dinv, b1);
  k_gemm<HID, HID, false><<<(N_NODES + 63) / 64, 256, 0, stream>>>(bufB, W2, bufA, nullptr);
  k_agg<<<N_NODES * HID / 256, 256, 0, stream>>>(bufA, bufB, ptr, srow, dinv, b2);
  k_gemm<HID, NCOMM, true><<<(N_NODES + 127) / 128, 256, 0, stream>>>(bufB, Wfc, out, bfc);
}

// Round 4
// 307.726 us; speedup vs baseline: 3.5001x; 1.2128x over previous
//
#include <hip/hip_runtime.h>
#include <hip/hip_fp16.h>
#include <math.h>

#define N_NODES 100000
#define N_EDGES 1600000
#define IN_DIM  128
#define HID     64
#define NCOMM   32
#define NBLK_SCAN 98    // ceil(100000/1024)
#define NB        391   // ceil(100000/256) coarse buckets
#define BSHIFT    8     // 256 nodes per bucket
#define EPB       4096  // edges per block in binning kernels
#define NBIN_BLK  391   // ceil(1600000/4096)

// ---------- edge dtype detection (int64 vs int32), parallel, deterministic ----------
__global__ void k_detect(const unsigned int* __restrict__ e, int* __restrict__ flag) {
  int lane = threadIdx.x;  // 64 lanes
  unsigned v = 0;
  #pragma unroll
  for (int i = 0; i < 4; ++i) v |= e[2 * (lane * 4 + i) + 1];
  unsigned long long nz = __ballot(v != 0u);
  if (lane == 0) *flag = (nz == 0ull) ? 1 : 0;  // 1 => int64 layout
}

__device__ __forceinline__ int load_idx(const int* e32, long long pos, int is64) {
  if (is64) return (int)(((const long long*)e32)[pos]);
  return e32[pos];
}

// ---------- coarse bucket histogram (LDS counters, few global atomics) ----------
__global__ __launch_bounds__(256) void k_bhist(const int* __restrict__ e, int* __restrict__ bcnt,
                                               const int* __restrict__ flag) {
  __shared__ int cnt[NB];
  for (int i = threadIdx.x; i < NB; i += 256) cnt[i] = 0;
  __syncthreads();
  int is64 = *flag;
  long long base = (long long)blockIdx.x * EPB;
  #pragma unroll
  for (int j = 0; j < EPB / 256; ++j) {
    long long eid = base + j * 256 + threadIdx.x;
    if (eid < N_EDGES) {
      int c = load_idx(e, (long long)N_EDGES + eid, is64);
      atomicAdd(&cnt[c >> BSHIFT], 1);
    }
  }
  __syncthreads();
  for (int b = threadIdx.x; b < NB; b += 256)
    if (cnt[b]) atomicAdd(&bcnt[b], cnt[b]);
}

// ---------- scan coarse buckets -> bptr, bcur ----------
__global__ __launch_bounds__(512) void k_bscan(const int* __restrict__ bcnt, int* __restrict__ bptr,
                                               int* __restrict__ bcur) {
  __shared__ int sm[512];
  int t = threadIdx.x;
  int v = (t < NB) ? bcnt[t] : 0;
  sm[t] = v;
  __syncthreads();
  for (int off = 1; off < 512; off <<= 1) {
    int u = (t >= off) ? sm[t - off] : 0;
    __syncthreads();
    sm[t] += u;
    __syncthreads();
  }
  if (t < NB) {
    int ex = sm[t] - v;
    bptr[t] = ex;
    bcur[t] = ex;
  }
  if (t == 0) bptr[NB] = N_EDGES;
}

// ---------- bin edges into coarse buckets as packed (r,c) ----------
__global__ __launch_bounds__(256) void k_bin(const int* __restrict__ e, int* __restrict__ bcur,
                                             uint2* __restrict__ ebuf, const int* __restrict__ flag) {
  __shared__ int cnt[NB];
  __shared__ int base[NB];
  for (int i = threadIdx.x; i < NB; i += 256) cnt[i] = 0;
  __syncthreads();
  int is64 = *flag;
  long long eb = (long long)blockIdx.x * EPB;
  int rr[EPB / 256], cc[EPB / 256], lr[EPB / 256];
  #pragma unroll
  for (int j = 0; j < EPB / 256; ++j) {
    long long eid = eb + j * 256 + threadIdx.x;
    if (eid < N_EDGES) {
      rr[j] = load_idx(e, eid, is64);
      cc[j] = load_idx(e, (long long)N_EDGES + eid, is64);
      lr[j] = atomicAdd(&cnt[cc[j] >> BSHIFT], 1);
    }
  }
  __syncthreads();
  for (int b = threadIdx.x; b < NB; b += 256)
    base[b] = cnt[b] ? atomicAdd(&bcur[b], cnt[b]) : 0;
  __syncthreads();
  #pragma unroll
  for (int j = 0; j < EPB / 256; ++j) {
    long long eid = eb + j * 256 + threadIdx.x;
    if (eid < N_EDGES) {
      int pos = base[cc[j] >> BSHIFT] + lr[j];
      ebuf[pos] = make_uint2((unsigned)rr[j], (unsigned)cc[j]);
    }
  }
}

// ---------- per-bucket degree histogram (LDS, no global atomics) + dinv ----------
__global__ __launch_bounds__(256) void k_deg(const uint2* __restrict__ ebuf, const int* __restrict__ bptr,
                                             int* __restrict__ deg, float* __restrict__ dinv) {
  __shared__ int cnt[256];
  int b = blockIdx.x;
  int c0 = b << BSHIFT;
  cnt[threadIdx.x] = 0;
  __syncthreads();
  int s = bptr[b], epos = bptr[b + 1];
  for (int i = s + threadIdx.x; i < epos; i += 256)
    atomicAdd(&cnt[(int)ebuf[i].y - c0], 1);
  __syncthreads();
  int node = c0 + threadIdx.x;
  if (node < N_NODES) {
    int d = cnt[threadIdx.x];
    deg[node] = d;
    dinv[node] = rsqrtf((float)d + 1.0f);  // +1 = self loop; always > 0
  }
}

// ---------- two-level scan of deg -> ptr ----------
__global__ __launch_bounds__(1024) void k_scan_a(const int* __restrict__ deg, int* __restrict__ excl,
                                                 int* __restrict__ part) {
  __shared__ int sm[1024];
  int t = threadIdx.x;
  int i = blockIdx.x * 1024 + t;
  int d = (i < N_NODES) ? deg[i] : 0;
  sm[t] = d;
  __syncthreads();
  for (int off = 1; off < 1024; off <<= 1) {
    int u = (t >= off) ? sm[t - off] : 0;
    __syncthreads();
    sm[t] += u;
    __syncthreads();
  }
  if (i < N_NODES) excl[i] = sm[t] - d;
  if (t == 1023) part[blockIdx.x] = sm[1023];
}

__global__ __launch_bounds__(128) void k_scan_b(int* __restrict__ part) {
  __shared__ int sm[128];
  int t = threadIdx.x;
  int v = (t < NBLK_SCAN) ? part[t] : 0;
  sm[t] = v;
  __syncthreads();
  for (int off = 1; off < 128; off <<= 1) {
    int u = (t >= off) ? sm[t - off] : 0;
    __syncthreads();
    sm[t] += u;
    __syncthreads();
  }
  if (t < NBLK_SCAN) part[t] = sm[t] - v;  // exclusive
}

__global__ __launch_bounds__(1024) void k_scan_c(const int* __restrict__ excl, const int* __restrict__ part,
                                                 int* __restrict__ ptr) {
  int i = blockIdx.x * 1024 + threadIdx.x;
  if (i < N_NODES) ptr[i] = excl[i] + part[blockIdx.x];
  if (i == 0) ptr[N_NODES] = N_EDGES;
}

// ---------- fine sort within bucket: LDS cursors, write packed (r, w=dinv[r]*dinv[c]) ----------
__global__ __launch_bounds__(1024) void k_fsort(const uint2* __restrict__ ebuf, const int* __restrict__ bptr,
                                                const int* __restrict__ ptr, const float* __restrict__ dinv,
                                                uint2* __restrict__ pk) {
  __shared__ int cur[256];
  int b = blockIdx.x;
  int c0 = b << BSHIFT;
  if (threadIdx.x < 256) {
    int node = c0 + threadIdx.x;
    cur[threadIdx.x] = (node < N_NODES) ? ptr[node] : 0;
  }
  __syncthreads();
  int s = bptr[b], epos = bptr[b + 1];
  for (int i = s + (int)threadIdx.x; i < epos; i += 1024) {
    uint2 ed = ebuf[i];
    int r = (int)ed.x, c = (int)ed.y;
    float w = dinv[r] * dinv[c];
    int pos = atomicAdd(&cur[c - c0], 1);
    pk[pos] = make_uint2((unsigned)r, __float_as_uint(w));
  }
}

// ---------- dense GEMM: Y[n,M] = X[n,K] @ W[K,M]; each thread: 4 nodes x 4 cols ----------
__device__ __forceinline__ float4 epil(float4 a, float4 bv, bool fin) {
  if (fin) {
    a.x = 1.f / (1.f + __expf(-(a.x + bv.x)));
    a.y = 1.f / (1.f + __expf(-(a.y + bv.y)));
    a.z = 1.f / (1.f + __expf(-(a.z + bv.z)));
    a.w = 1.f / (1.f + __expf(-(a.w + bv.w)));
  }
  return a;
}

__device__ __forceinline__ void store_out(void* Y, int M, int node, int cg, float4 a, bool outh) {
  if (outh) {
    __half2 h0 = __floats2half2_rn(a.x, a.y);
    __half2 h1 = __floats2half2_rn(a.z, a.w);
    uint2 pv;
    pv.x = *(unsigned*)&h0;
    pv.y = *(unsigned*)&h1;
    *(uint2*)((char*)Y + (size_t)node * (M * 2) + cg * 8) = pv;
  } else {
    ((float4*)((float*)Y + (size_t)node * M))[cg] = a;
  }
}

#define DOT4(acc, xv)                                          \
  acc.x += xv.x * w0.x + xv.y * w1.x + xv.z * w2.x + xv.w * w3.x; \
  acc.y += xv.x * w0.y + xv.y * w1.y + xv.z * w2.y + xv.w * w3.y; \
  acc.z += xv.x * w0.z + xv.y * w1.z + xv.z * w2.z + xv.w * w3.z; \
  acc.w += xv.x * w0.w + xv.y * w1.w + xv.z * w2.w + xv.w * w3.w;

template<int K, int M, bool FINAL, bool OUTH>
__global__ __launch_bounds__(256) void k_gemm(const float* __restrict__ X, const float* __restrict__ W,
                                              void* __restrict__ Y, const float* __restrict__ bias) {
  constexpr int CG  = M / 4;      // float4 col-groups: 16 (M=64) or 8 (M=32)
  constexpr int NG  = 256 / CG;   // node-groups per block
  constexpr int NPT = 4;          // nodes per thread
  constexpr int NPB = NG * NPT;   // nodes per block: 64 or 128
  __shared__ float4 w4[K * CG];
  const float4* Wv = (const float4*)W;
  for (int i = threadIdx.x; i < K * CG; i += 256) w4[i] = Wv[i];
  __syncthreads();
  const int cg = threadIdx.x % CG;
  const int ng = threadIdx.x / CG;
  const int base = blockIdx.x * NPB + ng * NPT;
  if (base >= N_NODES) return;
  float4 bv = {0, 0, 0, 0};
  if (FINAL) bv = ((const float4*)bias)[cg];

  if (base + NPT <= N_NODES) {
    const float4* xr = (const float4*)(X + (size_t)base * K);
    float4 a0 = {0,0,0,0}, a1 = {0,0,0,0}, a2 = {0,0,0,0}, a3 = {0,0,0,0};
    #pragma unroll 2
    for (int k4 = 0; k4 < K / 4; ++k4) {
      float4 w0 = w4[(k4 * 4 + 0) * CG + cg];
      float4 w1 = w4[(k4 * 4 + 1) * CG + cg];
      float4 w2 = w4[(k4 * 4 + 2) * CG + cg];
      float4 w3 = w4[(k4 * 4 + 3) * CG + cg];
      float4 x0 = xr[0 * (K / 4) + k4];
      float4 x1 = xr[1 * (K / 4) + k4];
      float4 x2 = xr[2 * (K / 4) + k4];
      float4 x3 = xr[3 * (K / 4) + k4];
      DOT4(a0, x0);
      DOT4(a1, x1);
      DOT4(a2, x2);
      DOT4(a3, x3);
    }
    store_out(Y, M, base + 0, cg, epil(a0, bv, FINAL), OUTH);
    store_out(Y, M, base + 1, cg, epil(a1, bv, FINAL), OUTH);
    store_out(Y, M, base + 2, cg, epil(a2, bv, FINAL), OUTH);
    store_out(Y, M, base + 3, cg, epil(a3, bv, FINAL), OUTH);
  } else {
    for (int n = 0; n < N_NODES - base; ++n) {
      const float4* xr = (const float4*)(X + (size_t)(base + n) * K);
      float4 a = {0, 0, 0, 0};
      for (int k4 = 0; k4 < K / 4; ++k4) {
        float4 w0 = w4[(k4 * 4 + 0) * CG + cg];
        float4 w1 = w4[(k4 * 4 + 1) * CG + cg];
        float4 w2 = w4[(k4 * 4 + 2) * CG + cg];
        float4 w3 = w4[(k4 * 4 + 3) * CG + cg];
        float4 xv = xr[k4];
        DOT4(a, xv);
      }
      store_out(Y, M, base + n, cg, epil(a, bv, FINAL), OUTH);
    }
  }
}

// ---------- pull aggregation, fp16 gather rows, 4 edges per wave ----------
// O[c] = relu( sum_in H[r]*w_e + H[c]*dinv[c]^2 + b ),  w_e precomputed in pk
__global__ __launch_bounds__(256) void k_agg(const __half* __restrict__ H, float* __restrict__ O,
                                             const int* __restrict__ ptr, const uint2* __restrict__ pk,
                                             const float* __restrict__ dinv, const float* __restrict__ bias) {
  int wid  = (blockIdx.x * 256 + threadIdx.x) >> 6;  // node (one wave per node)
  int lane = threadIdx.x & 63;
  if (wid >= N_NODES) return;
  const int q  = lane >> 4;   // quarter-wave id: which edge of a group of 4
  const int fl = lane & 15;   // feature quad: features 4*fl .. 4*fl+3
  int s = ptr[wid], e = ptr[wid + 1];
  float4 acc = {0.f, 0.f, 0.f, 0.f};
  for (int j = s; j < e; j += 4) {
    int idx = j + q;
    bool valid = idx < e;
    uint2 ent = pk[valid ? idx : (e - 1)];
    float w = valid ? __uint_as_float(ent.y) : 0.f;
    int r = (int)ent.x;
    uint2 hb = *(const uint2*)((const char*)H + (size_t)r * (HID * 2) + fl * 8);
    __half2 p0 = *(__half2*)&hb.x;
    __half2 p1 = *(__half2*)&hb.y;
    float2 f0 = __half22float2(p0);
    float2 f1 = __half22float2(p1);
    acc.x += f0.x * w;
    acc.y += f0.y * w;
    acc.z += f1.x * w;
    acc.w += f1.y * w;
  }
  if (q == 0) {  // self loop, counted once
    float di = dinv[wid];
    float w = di * di;
    uint2 hb = *(const uint2*)((const char*)H + (size_t)wid * (HID * 2) + fl * 8);
    __half2 p0 = *(__half2*)&hb.x;
    __half2 p1 = *(__half2*)&hb.y;
    float2 f0 = __half22float2(p0);
    float2 f1 = __half22float2(p1);
    acc.x += f0.x * w;
    acc.y += f0.y * w;
    acc.z += f1.x * w;
    acc.w += f1.y * w;
  }
  // merge the 4 quarter-waves
  acc.x += __shfl_xor(acc.x, 16, 64);
  acc.y += __shfl_xor(acc.y, 16, 64);
  acc.z += __shfl_xor(acc.z, 16, 64);
  acc.w += __shfl_xor(acc.w, 16, 64);
  acc.x += __shfl_xor(acc.x, 32, 64);
  acc.y += __shfl_xor(acc.y, 32, 64);
  acc.z += __shfl_xor(acc.z, 32, 64);
  acc.w += __shfl_xor(acc.w, 32, 64);
  if (lane < 16) {
    float4 b = ((const float4*)bias)[fl];
    float4 o;
    o.x = fmaxf(acc.x + b.x, 0.f);
    o.y = fmaxf(acc.y + b.y, 0.f);
    o.z = fmaxf(acc.z + b.z, 0.f);
    o.w = fmaxf(acc.w + b.w, 0.f);
    ((float4*)(O + (size_t)wid * HID))[fl] = o;
  }
}

extern "C" void kernel_launch(void* const* d_in, const int* in_sizes, int n_in,
                              void* d_out, int out_size, void* d_ws, size_t ws_size,
                              hipStream_t stream) {
  const float* x   = (const float*)d_in[0];
  const int*   e   = (const int*)d_in[1];
  const float* W1  = (const float*)d_in[2];
  const float* b1  = (const float*)d_in[3];
  const float* W2  = (const float*)d_in[4];
  const float* b2  = (const float*)d_in[5];
  const float* Wfc = (const float*)d_in[6];
  const float* bfc = (const float*)d_in[7];
  float* out = (float*)d_out;

  // workspace layout (bytes) — total < 53 MB
  char* ws = (char*)d_ws;
  __half* hbuf = (__half*)(ws);             // N*64 fp16 = 12,800,000 (gather rows)
  float*  abuf = (float*) (ws + 12800000);  // N*64 f32  = 25,600,000 (agg outputs)
  uint2*  ebuf = (uint2*) (ws + 12800000);  // E uint2 (ALIASED on abuf; dead after fsort)
  uint2*  pk   = (uint2*) (ws + 38400000);  // E uint2 packed (r, w) = 12,800,000
  int*    deg  = (int*)   (ws + 51200000);  // N i32
  float*  dinv = (float*) (ws + 51600000);  // N f32
  int*    ptr  = (int*)   (ws + 52000000);  // (N+1) i32
  int*    excl = (int*)   (ws + 52400064);  // N i32 scan temp
  int*    flag = (int*)   (ws + 52800064);  // 1 i32
  int*    part = (int*)   (ws + 52800128);  // NBLK_SCAN i32
  int*    bcnt = (int*)   (ws + 52800576);  // NB i32
  int*    bptr = (int*)   (ws + 52802176);  // NB+1 i32
  int*    bcur = (int*)   (ws + 52803776);  // NB i32

  hipMemsetAsync(bcnt, 0, NB * sizeof(int), stream);
  k_detect<<<1, 64, 0, stream>>>((const unsigned int*)e, flag);
  k_bhist<<<NBIN_BLK, 256, 0, stream>>>(e, bcnt, flag);
  k_bscan<<<1, 512, 0, stream>>>(bcnt, bptr, bcur);
  k_bin<<<NBIN_BLK, 256, 0, stream>>>(e, bcur, ebuf, flag);
  k_deg<<<NB, 256, 0, stream>>>(ebuf, bptr, deg, dinv);
  k_scan_a<<<NBLK_SCAN, 1024, 0, stream>>>(deg, excl, part);
  k_scan_b<<<1, 128, 0, stream>>>(part);
  k_scan_c<<<NBLK_SCAN, 1024, 0, stream>>>(excl, part, ptr);
  k_fsort<<<NB, 1024, 0, stream>>>(ebuf, bptr, ptr, dinv, pk);

  k_gemm<IN_DIM, HID, false, true><<<(N_NODES + 63) / 64, 256, 0, stream>>>(x, W1, hbuf, nullptr);
  k_agg<<<N_NODES * 64 / 256, 256, 0, stream>>>(hbuf, abuf, ptr, pk, dinv, b1);
  k_gemm<HID, HID, false, true><<<(N_NODES + 63) / 64, 256, 0, stream>>>(abuf, W2, hbuf, nullptr);
  k_agg<<<N_NODES * 64 / 256, 256, 0, stream>>>(hbuf, abuf, ptr, pk, dinv, b2);
  k_gemm<HID, NCOMM, true, false><<<(N_NODES + 127) / 128, 256, 0, stream>>>(abuf, Wfc, out, bfc);
}

// Round 5
// 262.076 us; speedup vs baseline: 4.1097x; 1.1742x over previous
//
#include <hip/hip_runtime.h>
#include <hip/hip_fp16.h>
#include <math.h>

#define N_NODES 100000
#define N_EDGES 1600000
#define IN_DIM  128
#define HID     64
#define NCOMM   32
#define NB        391   // ceil(100000/256) coarse buckets
#define BSHIFT    8     // 256 nodes per bucket
#define EPB       4096  // edges per block in binning kernels
#define NBIN_BLK  391   // ceil(1600000/4096)

// ---------- edge dtype detection (int64 vs int32), parallel, deterministic ----------
__global__ void k_detect(const unsigned int* __restrict__ e, int* __restrict__ flag) {
  int lane = threadIdx.x;  // 64 lanes
  unsigned v = 0;
  #pragma unroll
  for (int i = 0; i < 4; ++i) v |= e[2 * (lane * 4 + i) + 1];
  unsigned long long nz = __ballot(v != 0u);
  if (lane == 0) *flag = (nz == 0ull) ? 1 : 0;  // 1 => int64 layout
}

__device__ __forceinline__ int load_idx(const int* e32, long long pos, int is64) {
  if (is64) return (int)(((const long long*)e32)[pos]);
  return e32[pos];
}

// ---------- coarse bucket histogram (LDS counters, few global atomics) ----------
__global__ __launch_bounds__(256) void k_bhist(const int* __restrict__ e, int* __restrict__ bcnt,
                                               const int* __restrict__ flag) {
  __shared__ int cnt[NB];
  for (int i = threadIdx.x; i < NB; i += 256) cnt[i] = 0;
  __syncthreads();
  int is64 = *flag;
  long long base = (long long)blockIdx.x * EPB;
  #pragma unroll
  for (int j = 0; j < EPB / 256; ++j) {
    long long eid = base + j * 256 + threadIdx.x;
    if (eid < N_EDGES) {
      int c = load_idx(e, (long long)N_EDGES + eid, is64);
      atomicAdd(&cnt[c >> BSHIFT], 1);
    }
  }
  __syncthreads();
  for (int b = threadIdx.x; b < NB; b += 256)
    if (cnt[b]) atomicAdd(&bcnt[b], cnt[b]);
}

// ---------- scan coarse buckets -> bptr, bcur ----------
__global__ __launch_bounds__(512) void k_bscan(const int* __restrict__ bcnt, int* __restrict__ bptr,
                                               int* __restrict__ bcur) {
  __shared__ int sm[512];
  int t = threadIdx.x;
  int v = (t < NB) ? bcnt[t] : 0;
  sm[t] = v;
  __syncthreads();
  for (int off = 1; off < 512; off <<= 1) {
    int u = (t >= off) ? sm[t - off] : 0;
    __syncthreads();
    sm[t] += u;
    __syncthreads();
  }
  if (t < NB) {
    int ex = sm[t] - v;
    bptr[t] = ex;
    bcur[t] = ex;
  }
  if (t == 0) bptr[NB] = N_EDGES;
}

// ---------- bin edges into coarse buckets as packed (r,c) ----------
__global__ __launch_bounds__(256) void k_bin(const int* __restrict__ e, int* __restrict__ bcur,
                                             uint2* __restrict__ ebuf, const int* __restrict__ flag) {
  __shared__ int cnt[NB];
  __shared__ int base[NB];
  for (int i = threadIdx.x; i < NB; i += 256) cnt[i] = 0;
  __syncthreads();
  int is64 = *flag;
  long long eb = (long long)blockIdx.x * EPB;
  int rr[EPB / 256], cc[EPB / 256], lr[EPB / 256];
  #pragma unroll
  for (int j = 0; j < EPB / 256; ++j) {
    long long eid = eb + j * 256 + threadIdx.x;
    if (eid < N_EDGES) {
      rr[j] = load_idx(e, eid, is64);
      cc[j] = load_idx(e, (long long)N_EDGES + eid, is64);
      lr[j] = atomicAdd(&cnt[cc[j] >> BSHIFT], 1);
    }
  }
  __syncthreads();
  for (int b = threadIdx.x; b < NB; b += 256)
    base[b] = cnt[b] ? atomicAdd(&bcur[b], cnt[b]) : 0;
  __syncthreads();
  #pragma unroll
  for (int j = 0; j < EPB / 256; ++j) {
    long long eid = eb + j * 256 + threadIdx.x;
    if (eid < N_EDGES) {
      int pos = base[cc[j] >> BSHIFT] + lr[j];
      ebuf[pos] = make_uint2((unsigned)rr[j], (unsigned)cc[j]);
    }
  }
}

// ---------- per-bucket degree histogram + dinv + ptr (fused local scan; base = bptr[b]) ----------
__global__ __launch_bounds__(256) void k_deg(const uint2* __restrict__ ebuf, const int* __restrict__ bptr,
                                             float* __restrict__ dinv, int* __restrict__ ptr) {
  __shared__ int cnt[256];
  __shared__ int scn[256];
  int t = threadIdx.x;
  int b = blockIdx.x;
  int c0 = b << BSHIFT;
  cnt[t] = 0;
  __syncthreads();
  int s = bptr[b], epos = bptr[b + 1];
  for (int i = s + t; i < epos; i += 256)
    atomicAdd(&cnt[(int)ebuf[i].y - c0], 1);
  __syncthreads();
  int d = cnt[t];
  scn[t] = d;
  __syncthreads();
  for (int off = 1; off < 256; off <<= 1) {
    int u = (t >= off) ? scn[t - off] : 0;
    __syncthreads();
    scn[t] += u;
    __syncthreads();
  }
  int node = c0 + t;
  if (node < N_NODES) {
    dinv[node] = rsqrtf((float)d + 1.0f);   // +1 = self loop; always > 0
    ptr[node] = bptr[b] + scn[t] - d;       // global exclusive offset
  }
  if (b == NB - 1 && t == 0) ptr[N_NODES] = N_EDGES;
}

// ---------- fine sort within bucket: LDS cursors, write packed (r, w=dinv[r]*dinv[c]) ----------
__global__ __launch_bounds__(1024) void k_fsort(const uint2* __restrict__ ebuf, const int* __restrict__ bptr,
                                                const int* __restrict__ ptr, const float* __restrict__ dinv,
                                                uint2* __restrict__ pk) {
  __shared__ int cur[256];
  int b = blockIdx.x;
  int c0 = b << BSHIFT;
  if (threadIdx.x < 256) {
    int node = c0 + threadIdx.x;
    cur[threadIdx.x] = (node < N_NODES) ? ptr[node] : 0;
  }
  __syncthreads();
  int s = bptr[b], epos = bptr[b + 1];
  for (int i = s + (int)threadIdx.x; i < epos; i += 1024) {
    uint2 ed = ebuf[i];
    int r = (int)ed.x, c = (int)ed.y;
    float w = dinv[r] * dinv[c];
    int pos = atomicAdd(&cur[c - c0], 1);
    pk[pos] = make_uint2((unsigned)r, __float_as_uint(w));
  }
}

// ---------- dense GEMM: Y[n,M] = X[n,K] @ W[K,M]; each thread: 4 nodes x 4 cols ----------
__device__ __forceinline__ float4 epil(float4 a, float4 bv, bool fin) {
  if (fin) {
    a.x = 1.f / (1.f + __expf(-(a.x + bv.x)));
    a.y = 1.f / (1.f + __expf(-(a.y + bv.y)));
    a.z = 1.f / (1.f + __expf(-(a.z + bv.z)));
    a.w = 1.f / (1.f + __expf(-(a.w + bv.w)));
  }
  return a;
}

__device__ __forceinline__ void store_out(void* Y, int M, int node, int cg, float4 a, bool outh) {
  if (outh) {
    __half2 h0 = __floats2half2_rn(a.x, a.y);
    __half2 h1 = __floats2half2_rn(a.z, a.w);
    uint2 pv;
    pv.x = *(unsigned*)&h0;
    pv.y = *(unsigned*)&h1;
    *(uint2*)((char*)Y + (size_t)node * (M * 2) + cg * 8) = pv;
  } else {
    ((float4*)((float*)Y + (size_t)node * M))[cg] = a;
  }
}

// load 4 consecutive features (k4*4) of row `node` as float4, from fp32 or fp16 storage
__device__ __forceinline__ float4 ldx(const void* X, int K, int node, int k4, bool inh) {
  if (inh) {
    uint2 u = *(const uint2*)((const char*)X + (size_t)node * (K * 2) + k4 * 8);
    __half2 a = *(__half2*)&u.x;
    __half2 b = *(__half2*)&u.y;
    float2 fa = __half22float2(a);
    float2 fb = __half22float2(b);
    return make_float4(fa.x, fa.y, fb.x, fb.y);
  } else {
    return ((const float4*)((const float*)X + (size_t)node * K))[k4];
  }
}

#define DOT4(acc, xv)                                          \
  acc.x += xv.x * w0.x + xv.y * w1.x + xv.z * w2.x + xv.w * w3.x; \
  acc.y += xv.x * w0.y + xv.y * w1.y + xv.z * w2.y + xv.w * w3.y; \
  acc.z += xv.x * w0.z + xv.y * w1.z + xv.z * w2.z + xv.w * w3.z; \
  acc.w += xv.x * w0.w + xv.y * w1.w + xv.z * w2.w + xv.w * w3.w;

template<int K, int M, bool FINAL, bool OUTH, bool INH>
__global__ __launch_bounds__(256) void k_gemm(const void* __restrict__ X, const float* __restrict__ W,
                                              void* __restrict__ Y, const float* __restrict__ bias) {
  constexpr int CG  = M / 4;      // float4 col-groups: 16 (M=64) or 8 (M=32)
  constexpr int NG  = 256 / CG;   // node-groups per block
  constexpr int NPT = 4;          // nodes per thread
  constexpr int NPB = NG * NPT;   // nodes per block: 64 or 128
  __shared__ float4 w4[K * CG];
  const float4* Wv = (const float4*)W;
  for (int i = threadIdx.x; i < K * CG; i += 256) w4[i] = Wv[i];
  __syncthreads();
  const int cg = threadIdx.x % CG;
  const int ng = threadIdx.x / CG;
  const int base = blockIdx.x * NPB + ng * NPT;
  if (base >= N_NODES) return;
  float4 bv = {0, 0, 0, 0};
  if (FINAL) bv = ((const float4*)bias)[cg];

  if (base + NPT <= N_NODES) {
    float4 a0 = {0,0,0,0}, a1 = {0,0,0,0}, a2 = {0,0,0,0}, a3 = {0,0,0,0};
    #pragma unroll 2
    for (int k4 = 0; k4 < K / 4; ++k4) {
      float4 w0 = w4[(k4 * 4 + 0) * CG + cg];
      float4 w1 = w4[(k4 * 4 + 1) * CG + cg];
      float4 w2 = w4[(k4 * 4 + 2) * CG + cg];
      float4 w3 = w4[(k4 * 4 + 3) * CG + cg];
      float4 x0 = ldx(X, K, base + 0, k4, INH);
      float4 x1 = ldx(X, K, base + 1, k4, INH);
      float4 x2 = ldx(X, K, base + 2, k4, INH);
      float4 x3 = ldx(X, K, base + 3, k4, INH);
      DOT4(a0, x0);
      DOT4(a1, x1);
      DOT4(a2, x2);
      DOT4(a3, x3);
    }
    store_out(Y, M, base + 0, cg, epil(a0, bv, FINAL), OUTH);
    store_out(Y, M, base + 1, cg, epil(a1, bv, FINAL), OUTH);
    store_out(Y, M, base + 2, cg, epil(a2, bv, FINAL), OUTH);
    store_out(Y, M, base + 3, cg, epil(a3, bv, FINAL), OUTH);
  } else {
    for (int n = 0; n < N_NODES - base; ++n) {
      float4 a = {0, 0, 0, 0};
      for (int k4 = 0; k4 < K / 4; ++k4) {
        float4 w0 = w4[(k4 * 4 + 0) * CG + cg];
        float4 w1 = w4[(k4 * 4 + 1) * CG + cg];
        float4 w2 = w4[(k4 * 4 + 2) * CG + cg];
        float4 w3 = w4[(k4 * 4 + 3) * CG + cg];
        float4 xv = ldx(X, K, base + n, k4, INH);
        DOT4(a, xv);
      }
      store_out(Y, M, base + n, cg, epil(a, bv, FINAL), OUTH);
    }
  }
}

// ---------- pull aggregation, fp16 in/out, 8 edges per wave, unroll 2 ----------
// O[c] = relu( sum_in H[r]*w_e + H[c]*dinv[c]^2 + b ),  w_e precomputed in pk
__device__ __forceinline__ void acc8(float* acc, uint4 h, float w) {
  __half2 p0 = *(__half2*)&h.x;
  __half2 p1 = *(__half2*)&h.y;
  __half2 p2 = *(__half2*)&h.z;
  __half2 p3 = *(__half2*)&h.w;
  float2 f0 = __half22float2(p0);
  float2 f1 = __half22float2(p1);
  float2 f2 = __half22float2(p2);
  float2 f3 = __half22float2(p3);
  acc[0] += f0.x * w; acc[1] += f0.y * w;
  acc[2] += f1.x * w; acc[3] += f1.y * w;
  acc[4] += f2.x * w; acc[5] += f2.y * w;
  acc[6] += f3.x * w; acc[7] += f3.y * w;
}

__global__ __launch_bounds__(256) void k_agg(const __half* __restrict__ H, __half* __restrict__ O,
                                             const int* __restrict__ ptr, const uint2* __restrict__ pk,
                                             const float* __restrict__ dinv, const float* __restrict__ bias) {
  int wid  = (blockIdx.x * 256 + threadIdx.x) >> 6;  // node (one wave per node)
  int lane = threadIdx.x & 63;
  if (wid >= N_NODES) return;
  const int q  = lane >> 3;   // edge slot 0..7
  const int fl = lane & 7;    // feature octet: features 8*fl .. 8*fl+7 (16 B)
  const char* Hb = (const char*)H;
  int s = ptr[wid], e = ptr[wid + 1];
  float acc[8] = {0.f, 0.f, 0.f, 0.f, 0.f, 0.f, 0.f, 0.f};
  for (int j = s; j < e; j += 16) {
    int i0 = j + q;
    int i1 = j + 8 + q;
    bool v0 = i0 < e;
    bool v1 = i1 < e;
    uint2 e0 = pk[v0 ? i0 : j];   // j < e inside loop, always valid
    uint2 e1 = pk[v1 ? i1 : j];
    float w0 = v0 ? __uint_as_float(e0.y) : 0.f;
    float w1 = v1 ? __uint_as_float(e1.y) : 0.f;
    uint4 h0 = *(const uint4*)(Hb + (size_t)e0.x * (HID * 2) + fl * 16);
    uint4 h1 = *(const uint4*)(Hb + (size_t)e1.x * (HID * 2) + fl * 16);
    acc8(acc, h0, w0);
    acc8(acc, h1, w1);
  }
  if (q == 0) {  // self loop, counted once
    float di = dinv[wid];
    uint4 hb = *(const uint4*)(Hb + (size_t)wid * (HID * 2) + fl * 16);
    acc8(acc, hb, di * di);
  }
  // merge the 8 edge slots
  #pragma unroll
  for (int m = 8; m < 64; m <<= 1) {
    #pragma unroll
    for (int i = 0; i < 8; ++i) acc[i] += __shfl_xor(acc[i], m, 64);
  }
  if (lane < 8) {
    float4 ba = ((const float4*)bias)[2 * fl + 0];
    float4 bb = ((const float4*)bias)[2 * fl + 1];
    __half2 o0 = __floats2half2_rn(fmaxf(acc[0] + ba.x, 0.f), fmaxf(acc[1] + ba.y, 0.f));
    __half2 o1 = __floats2half2_rn(fmaxf(acc[2] + ba.z, 0.f), fmaxf(acc[3] + ba.w, 0.f));
    __half2 o2 = __floats2half2_rn(fmaxf(acc[4] + bb.x, 0.f), fmaxf(acc[5] + bb.y, 0.f));
    __half2 o3 = __floats2half2_rn(fmaxf(acc[6] + bb.z, 0.f), fmaxf(acc[7] + bb.w, 0.f));
    uint4 pv;
    pv.x = *(unsigned*)&o0;
    pv.y = *(unsigned*)&o1;
    pv.z = *(unsigned*)&o2;
    pv.w = *(unsigned*)&o3;
    *(uint4*)((char*)O + (size_t)wid * (HID * 2) + fl * 16) = pv;
  }
}

extern "C" void kernel_launch(void* const* d_in, const int* in_sizes, int n_in,
                              void* d_out, int out_size, void* d_ws, size_t ws_size,
                              hipStream_t stream) {
  const float* x   = (const float*)d_in[0];
  const int*   e   = (const int*)d_in[1];
  const float* W1  = (const float*)d_in[2];
  const float* b1  = (const float*)d_in[3];
  const float* W2  = (const float*)d_in[4];
  const float* b2  = (const float*)d_in[5];
  const float* Wfc = (const float*)d_in[6];
  const float* bfc = (const float*)d_in[7];
  float* out = (float*)d_out;

  // workspace layout (bytes) — total < 40 MB
  char* ws = (char*)d_ws;
  __half* hbuf = (__half*)(ws);             // N*64 fp16 = 12,800,000 (gather rows)
  uint2*  ebuf = (uint2*) (ws);             // E uint2 (ALIASED on hbuf; dead before gemm1)
  uint2*  pk   = (uint2*) (ws + 12800000);  // E uint2 packed (r, w) = 12,800,000
  __half* abuf = (__half*)(ws + 25600000);  // N*64 fp16 = 12,800,000 (agg outputs)
  float*  dinv = (float*) (ws + 38400000);  // N f32
  int*    ptr  = (int*)   (ws + 38800000);  // (N+1) i32
  int*    flag = (int*)   (ws + 39200064);  // 1 i32
  int*    bcnt = (int*)   (ws + 39200128);  // NB i32
  int*    bptr = (int*)   (ws + 39201728);  // NB+1 i32
  int*    bcur = (int*)   (ws + 39203392);  // NB i32

  hipMemsetAsync(bcnt, 0, NB * sizeof(int), stream);
  k_detect<<<1, 64, 0, stream>>>((const unsigned int*)e, flag);
  k_bhist<<<NBIN_BLK, 256, 0, stream>>>(e, bcnt, flag);
  k_bscan<<<1, 512, 0, stream>>>(bcnt, bptr, bcur);
  k_bin<<<NBIN_BLK, 256, 0, stream>>>(e, bcur, ebuf, flag);
  k_deg<<<NB, 256, 0, stream>>>(ebuf, bptr, dinv, ptr);
  k_fsort<<<NB, 1024, 0, stream>>>(ebuf, bptr, ptr, dinv, pk);

  k_gemm<IN_DIM, HID, false, true, false><<<(N_NODES + 63) / 64, 256, 0, stream>>>(x, W1, hbuf, nullptr);
  k_agg<<<N_NODES * 64 / 256, 256, 0, stream>>>(hbuf, abuf, ptr, pk, dinv, b1);
  k_gemm<HID, HID, false, true, true><<<(N_NODES + 63) / 64, 256, 0, stream>>>(abuf, W2, hbuf, nullptr);
  k_agg<<<N_NODES * 64 / 256, 256, 0, stream>>>(hbuf, abuf, ptr, pk, dinv, b2);
  k_gemm<HID, NCOMM, true, false, true><<<(N_NODES + 127) / 128, 256, 0, stream>>>(abuf, Wfc, out, bfc);
}

// Round 6
// 238.175 us; speedup vs baseline: 4.5222x; 1.1004x over previous
//
#include <hip/hip_runtime.h>
#include <hip/hip_fp16.h>
#include <math.h>

#define N_NODES 100000
#define N_EDGES 1600000
#define IN_DIM  128
#define HID     64
#define NCOMM   32
#define NB        391   // ceil(100000/256) coarse buckets
#define BSHIFT    8     // 256 nodes per bucket
#define EPB       4096  // edges per block in binning kernels
#define NBIN_BLK  391   // ceil(1600000/4096)

// ---------- edge dtype detection (int64 vs int32), parallel, deterministic ----------
__global__ void k_detect(const unsigned int* __restrict__ e, int* __restrict__ flag) {
  int lane = threadIdx.x;  // 64 lanes
  unsigned v = 0;
  #pragma unroll
  for (int i = 0; i < 4; ++i) v |= e[2 * (lane * 4 + i) + 1];
  unsigned long long nz = __ballot(v != 0u);
  if (lane == 0) *flag = (nz == 0ull) ? 1 : 0;  // 1 => int64 layout
}

__device__ __forceinline__ int load_idx(const int* e32, long long pos, int is64) {
  if (is64) return (int)(((const long long*)e32)[pos]);
  return e32[pos];
}

// ---------- coarse bucket histogram (LDS counters, few global atomics) ----------
__global__ __launch_bounds__(256) void k_bhist(const int* __restrict__ e, int* __restrict__ bcnt,
                                               const int* __restrict__ flag) {
  __shared__ int cnt[NB];
  for (int i = threadIdx.x; i < NB; i += 256) cnt[i] = 0;
  __syncthreads();
  int is64 = *flag;
  long long base = (long long)blockIdx.x * EPB;
  #pragma unroll
  for (int j = 0; j < EPB / 256; ++j) {
    long long eid = base + j * 256 + threadIdx.x;
    if (eid < N_EDGES) {
      int c = load_idx(e, (long long)N_EDGES + eid, is64);
      atomicAdd(&cnt[c >> BSHIFT], 1);
    }
  }
  __syncthreads();
  for (int b = threadIdx.x; b < NB; b += 256)
    if (cnt[b]) atomicAdd(&bcnt[b], cnt[b]);
}

// ---------- scan coarse buckets -> bptr, bcur ----------
__global__ __launch_bounds__(512) void k_bscan(const int* __restrict__ bcnt, int* __restrict__ bptr,
                                               int* __restrict__ bcur) {
  __shared__ int sm[512];
  int t = threadIdx.x;
  int v = (t < NB) ? bcnt[t] : 0;
  sm[t] = v;
  __syncthreads();
  for (int off = 1; off < 512; off <<= 1) {
    int u = (t >= off) ? sm[t - off] : 0;
    __syncthreads();
    sm[t] += u;
    __syncthreads();
  }
  if (t < NB) {
    int ex = sm[t] - v;
    bptr[t] = ex;
    bcur[t] = ex;
  }
  if (t == 0) bptr[NB] = N_EDGES;
}

// ---------- bin edges into coarse buckets as packed (r,c) ----------
__global__ __launch_bounds__(256) void k_bin(const int* __restrict__ e, int* __restrict__ bcur,
                                             uint2* __restrict__ ebuf, const int* __restrict__ flag) {
  __shared__ int cnt[NB];
  __shared__ int base[NB];
  for (int i = threadIdx.x; i < NB; i += 256) cnt[i] = 0;
  __syncthreads();
  int is64 = *flag;
  long long eb = (long long)blockIdx.x * EPB;
  int rr[EPB / 256], cc[EPB / 256], lr[EPB / 256];
  #pragma unroll
  for (int j = 0; j < EPB / 256; ++j) {
    long long eid = eb + j * 256 + threadIdx.x;
    if (eid < N_EDGES) {
      rr[j] = load_idx(e, eid, is64);
      cc[j] = load_idx(e, (long long)N_EDGES + eid, is64);
      lr[j] = atomicAdd(&cnt[cc[j] >> BSHIFT], 1);
    }
  }
  __syncthreads();
  for (int b = threadIdx.x; b < NB; b += 256)
    base[b] = cnt[b] ? atomicAdd(&bcur[b], cnt[b]) : 0;
  __syncthreads();
  #pragma unroll
  for (int j = 0; j < EPB / 256; ++j) {
    long long eid = eb + j * 256 + threadIdx.x;
    if (eid < N_EDGES) {
      int pos = base[cc[j] >> BSHIFT] + lr[j];
      ebuf[pos] = make_uint2((unsigned)rr[j], (unsigned)cc[j]);
    }
  }
}

// ---------- per-bucket degree histogram + dinv + ptr (fused local scan; base = bptr[b]) ----------
__global__ __launch_bounds__(256) void k_deg(const uint2* __restrict__ ebuf, const int* __restrict__ bptr,
                                             float* __restrict__ dinv, int* __restrict__ ptr) {
  __shared__ int cnt[256];
  __shared__ int scn[256];
  int t = threadIdx.x;
  int b = blockIdx.x;
  int c0 = b << BSHIFT;
  cnt[t] = 0;
  __syncthreads();
  int s = bptr[b], epos = bptr[b + 1];
  for (int i = s + t; i < epos; i += 256)
    atomicAdd(&cnt[(int)ebuf[i].y - c0], 1);
  __syncthreads();
  int d = cnt[t];
  scn[t] = d;
  __syncthreads();
  for (int off = 1; off < 256; off <<= 1) {
    int u = (t >= off) ? scn[t - off] : 0;
    __syncthreads();
    scn[t] += u;
    __syncthreads();
  }
  int node = c0 + t;
  if (node < N_NODES) {
    dinv[node] = rsqrtf((float)d + 1.0f);   // +1 = self loop; always > 0
    ptr[node] = bptr[b] + scn[t] - d;       // global exclusive offset
  }
  if (b == NB - 1 && t == 0) ptr[N_NODES] = N_EDGES;
}

// ---------- fine sort within bucket: LDS cursors, write packed (r, w=dinv[r]*dinv[c]) ----------
__global__ __launch_bounds__(1024) void k_fsort(const uint2* __restrict__ ebuf, const int* __restrict__ bptr,
                                                const int* __restrict__ ptr, const float* __restrict__ dinv,
                                                uint2* __restrict__ pk) {
  __shared__ int cur[256];
  int b = blockIdx.x;
  int c0 = b << BSHIFT;
  if (threadIdx.x < 256) {
    int node = c0 + threadIdx.x;
    cur[threadIdx.x] = (node < N_NODES) ? ptr[node] : 0;
  }
  __syncthreads();
  int s = bptr[b], epos = bptr[b + 1];
  for (int i = s + (int)threadIdx.x; i < epos; i += 1024) {
    uint2 ed = ebuf[i];
    int r = (int)ed.x, c = (int)ed.y;
    float w = dinv[r] * dinv[c];
    int pos = atomicAdd(&cur[c - c0], 1);
    pk[pos] = make_uint2((unsigned)r, __float_as_uint(w));
  }
}

// ---------- dense GEMM: Y[n,M] = X[n,K] @ W[K,M]; each thread: 4 nodes x 4 cols ----------
__device__ __forceinline__ float4 epil(float4 a, float4 bv, bool fin) {
  if (fin) {
    a.x = 1.f / (1.f + __expf(-(a.x + bv.x)));
    a.y = 1.f / (1.f + __expf(-(a.y + bv.y)));
    a.z = 1.f / (1.f + __expf(-(a.z + bv.z)));
    a.w = 1.f / (1.f + __expf(-(a.w + bv.w)));
  }
  return a;
}

__device__ __forceinline__ void store_out(void* Y, int M, int node, int cg, float4 a, bool outh) {
  if (outh) {
    __half2 h0 = __floats2half2_rn(a.x, a.y);
    __half2 h1 = __floats2half2_rn(a.z, a.w);
    uint2 pv;
    pv.x = *(unsigned*)&h0;
    pv.y = *(unsigned*)&h1;
    *(uint2*)((char*)Y + (size_t)node * (M * 2) + cg * 8) = pv;
  } else {
    ((float4*)((float*)Y + (size_t)node * M))[cg] = a;
  }
}

// load 4 consecutive features (k4*4) of row `node` as float4, from fp32 or fp16 storage
__device__ __forceinline__ float4 ldx(const void* X, int K, int node, int k4, bool inh) {
  if (inh) {
    uint2 u = *(const uint2*)((const char*)X + (size_t)node * (K * 2) + k4 * 8);
    __half2 a = *(__half2*)&u.x;
    __half2 b = *(__half2*)&u.y;
    float2 fa = __half22float2(a);
    float2 fb = __half22float2(b);
    return make_float4(fa.x, fa.y, fb.x, fb.y);
  } else {
    return ((const float4*)((const float*)X + (size_t)node * K))[k4];
  }
}

#define DOT4(acc, xv)                                          \
  acc.x += xv.x * w0.x + xv.y * w1.x + xv.z * w2.x + xv.w * w3.x; \
  acc.y += xv.x * w0.y + xv.y * w1.y + xv.z * w2.y + xv.w * w3.y; \
  acc.z += xv.x * w0.z + xv.y * w1.z + xv.z * w2.z + xv.w * w3.z; \
  acc.w += xv.x * w0.w + xv.y * w1.w + xv.z * w2.w + xv.w * w3.w;

// __launch_bounds__(256, 4): 4 waves/SIMD min -> VGPR cap 128, keeps us off the
// 224-VGPR / 2-waves-per-SIMD occupancy cliff measured in round 5.
template<int K, int M, bool FINAL, bool OUTH, bool INH>
__global__ __launch_bounds__(256, 4) void k_gemm(const void* __restrict__ X, const float* __restrict__ W,
                                                 void* __restrict__ Y, const float* __restrict__ bias) {
  constexpr int CG  = M / 4;      // float4 col-groups: 16 (M=64) or 8 (M=32)
  constexpr int NG  = 256 / CG;   // node-groups per block
  constexpr int NPT = 4;          // nodes per thread
  constexpr int NPB = NG * NPT;   // nodes per block: 64 or 128
  __shared__ float4 w4[K * CG];
  const float4* Wv = (const float4*)W;
  for (int i = threadIdx.x; i < K * CG; i += 256) w4[i] = Wv[i];
  __syncthreads();
  const int cg = threadIdx.x % CG;
  const int ng = threadIdx.x / CG;
  const int base = blockIdx.x * NPB + ng * NPT;
  if (base >= N_NODES) return;
  float4 bv = {0, 0, 0, 0};
  if (FINAL) bv = ((const float4*)bias)[cg];

  if (base + NPT <= N_NODES) {
    float4 a0 = {0,0,0,0}, a1 = {0,0,0,0}, a2 = {0,0,0,0}, a3 = {0,0,0,0};
    #pragma unroll 1
    for (int k4 = 0; k4 < K / 4; ++k4) {
      float4 w0 = w4[(k4 * 4 + 0) * CG + cg];
      float4 w1 = w4[(k4 * 4 + 1) * CG + cg];
      float4 w2 = w4[(k4 * 4 + 2) * CG + cg];
      float4 w3 = w4[(k4 * 4 + 3) * CG + cg];
      float4 x0 = ldx(X, K, base + 0, k4, INH);
      float4 x1 = ldx(X, K, base + 1, k4, INH);
      float4 x2 = ldx(X, K, base + 2, k4, INH);
      float4 x3 = ldx(X, K, base + 3, k4, INH);
      DOT4(a0, x0);
      DOT4(a1, x1);
      DOT4(a2, x2);
      DOT4(a3, x3);
    }
    store_out(Y, M, base + 0, cg, epil(a0, bv, FINAL), OUTH);
    store_out(Y, M, base + 1, cg, epil(a1, bv, FINAL), OUTH);
    store_out(Y, M, base + 2, cg, epil(a2, bv, FINAL), OUTH);
    store_out(Y, M, base + 3, cg, epil(a3, bv, FINAL), OUTH);
  } else {
    for (int n = 0; n < N_NODES - base; ++n) {
      float4 a = {0, 0, 0, 0};
      #pragma unroll 1
      for (int k4 = 0; k4 < K / 4; ++k4) {
        float4 w0 = w4[(k4 * 4 + 0) * CG + cg];
        float4 w1 = w4[(k4 * 4 + 1) * CG + cg];
        float4 w2 = w4[(k4 * 4 + 2) * CG + cg];
        float4 w3 = w4[(k4 * 4 + 3) * CG + cg];
        float4 xv = ldx(X, K, base + n, k4, INH);
        DOT4(a, xv);
      }
      store_out(Y, M, base + n, cg, epil(a, bv, FINAL), OUTH);
    }
  }
}

// ---------- pull aggregation, fp16 in/out, 8 edges per wave, unroll 2 ----------
// O[c] = relu( sum_in H[r]*w_e + H[c]*dinv[c]^2 + b ),  w_e precomputed in pk
__device__ __forceinline__ void acc8(float* acc, uint4 h, float w) {
  __half2 p0 = *(__half2*)&h.x;
  __half2 p1 = *(__half2*)&h.y;
  __half2 p2 = *(__half2*)&h.z;
  __half2 p3 = *(__half2*)&h.w;
  float2 f0 = __half22float2(p0);
  float2 f1 = __half22float2(p1);
  float2 f2 = __half22float2(p2);
  float2 f3 = __half22float2(p3);
  acc[0] += f0.x * w; acc[1] += f0.y * w;
  acc[2] += f1.x * w; acc[3] += f1.y * w;
  acc[4] += f2.x * w; acc[5] += f2.y * w;
  acc[6] += f3.x * w; acc[7] += f3.y * w;
}

__global__ __launch_bounds__(256) void k_agg(const __half* __restrict__ H, __half* __restrict__ O,
                                             const int* __restrict__ ptr, const uint2* __restrict__ pk,
                                             const float* __restrict__ dinv, const float* __restrict__ bias) {
  int wid  = (blockIdx.x * 256 + threadIdx.x) >> 6;  // node (one wave per node)
  int lane = threadIdx.x & 63;
  if (wid >= N_NODES) return;
  const int q  = lane >> 3;   // edge slot 0..7
  const int fl = lane & 7;    // feature octet: features 8*fl .. 8*fl+7 (16 B)
  const char* Hb = (const char*)H;
  int s = ptr[wid], e = ptr[wid + 1];
  float acc[8] = {0.f, 0.f, 0.f, 0.f, 0.f, 0.f, 0.f, 0.f};
  for (int j = s; j < e; j += 16) {
    int i0 = j + q;
    int i1 = j + 8 + q;
    bool v0 = i0 < e;
    bool v1 = i1 < e;
    uint2 e0 = pk[v0 ? i0 : j];   // j < e inside loop, always valid
    uint2 e1 = pk[v1 ? i1 : j];
    float w0 = v0 ? __uint_as_float(e0.y) : 0.f;
    float w1 = v1 ? __uint_as_float(e1.y) : 0.f;
    uint4 h0 = *(const uint4*)(Hb + (size_t)e0.x * (HID * 2) + fl * 16);
    uint4 h1 = *(const uint4*)(Hb + (size_t)e1.x * (HID * 2) + fl * 16);
    acc8(acc, h0, w0);
    acc8(acc, h1, w1);
  }
  if (q == 0) {  // self loop, counted once
    float di = dinv[wid];
    uint4 hb = *(const uint4*)(Hb + (size_t)wid * (HID * 2) + fl * 16);
    acc8(acc, hb, di * di);
  }
  // merge the 8 edge slots
  #pragma unroll
  for (int m = 8; m < 64; m <<= 1) {
    #pragma unroll
    for (int i = 0; i < 8; ++i) acc[i] += __shfl_xor(acc[i], m, 64);
  }
  if (lane < 8) {
    float4 ba = ((const float4*)bias)[2 * fl + 0];
    float4 bb = ((const float4*)bias)[2 * fl + 1];
    __half2 o0 = __floats2half2_rn(fmaxf(acc[0] + ba.x, 0.f), fmaxf(acc[1] + ba.y, 0.f));
    __half2 o1 = __floats2half2_rn(fmaxf(acc[2] + ba.z, 0.f), fmaxf(acc[3] + ba.w, 0.f));
    __half2 o2 = __floats2half2_rn(fmaxf(acc[4] + bb.x, 0.f), fmaxf(acc[5] + bb.y, 0.f));
    __half2 o3 = __floats2half2_rn(fmaxf(acc[6] + bb.z, 0.f), fmaxf(acc[7] + bb.w, 0.f));
    uint4 pv;
    pv.x = *(unsigned*)&o0;
    pv.y = *(unsigned*)&o1;
    pv.z = *(unsigned*)&o2;
    pv.w = *(unsigned*)&o3;
    *(uint4*)((char*)O + (size_t)wid * (HID * 2) + fl * 16) = pv;
  }
}

extern "C" void kernel_launch(void* const* d_in, const int* in_sizes, int n_in,
                              void* d_out, int out_size, void* d_ws, size_t ws_size,
                              hipStream_t stream) {
  const float* x   = (const float*)d_in[0];
  const int*   e   = (const int*)d_in[1];
  const float* W1  = (const float*)d_in[2];
  const float* b1  = (const float*)d_in[3];
  const float* W2  = (const float*)d_in[4];
  const float* b2  = (const float*)d_in[5];
  const float* Wfc = (const float*)d_in[6];
  const float* bfc = (const float*)d_in[7];
  float* out = (float*)d_out;

  // workspace layout (bytes) — total < 40 MB
  char* ws = (char*)d_ws;
  __half* hbuf = (__half*)(ws);             // N*64 fp16 = 12,800,000 (gather rows)
  uint2*  ebuf = (uint2*) (ws);             // E uint2 (ALIASED on hbuf; dead before gemm1)
  uint2*  pk   = (uint2*) (ws + 12800000);  // E uint2 packed (r, w) = 12,800,000
  __half* abuf = (__half*)(ws + 25600000);  // N*64 fp16 = 12,800,000 (agg outputs)
  float*  dinv = (float*) (ws + 38400000);  // N f32
  int*    ptr  = (int*)   (ws + 38800000);  // (N+1) i32
  int*    flag = (int*)   (ws + 39200064);  // 1 i32
  int*    bcnt = (int*)   (ws + 39200128);  // NB i32
  int*    bptr = (int*)   (ws + 39201728);  // NB+1 i32
  int*    bcur = (int*)   (ws + 39203392);  // NB i32

  hipMemsetAsync(bcnt, 0, NB * sizeof(int), stream);
  k_detect<<<1, 64, 0, stream>>>((const unsigned int*)e, flag);
  k_bhist<<<NBIN_BLK, 256, 0, stream>>>(e, bcnt, flag);
  k_bscan<<<1, 512, 0, stream>>>(bcnt, bptr, bcur);
  k_bin<<<NBIN_BLK, 256, 0, stream>>>(e, bcur, ebuf, flag);
  k_deg<<<NB, 256, 0, stream>>>(ebuf, bptr, dinv, ptr);
  k_fsort<<<NB, 1024, 0, stream>>>(ebuf, bptr, ptr, dinv, pk);

  k_gemm<IN_DIM, HID, false, true, false><<<(N_NODES + 63) / 64, 256, 0, stream>>>(x, W1, hbuf, nullptr);
  k_agg<<<N_NODES * 64 / 256, 256, 0, stream>>>(hbuf, abuf, ptr, pk, dinv, b1);
  k_gemm<HID, HID, false, true, true><<<(N_NODES + 63) / 64, 256, 0, stream>>>(abuf, W2, hbuf, nullptr);
  k_agg<<<N_NODES * 64 / 256, 256, 0, stream>>>(hbuf, abuf, ptr, pk, dinv, b2);
  k_gemm<HID, NCOMM, true, false, true><<<(N_NODES + 127) / 128, 256, 0, stream>>>(abuf, Wfc, out, bfc);
}

// Round 7
// 204.829 us; speedup vs baseline: 5.2584x; 1.1628x over previous
//
#include <hip/hip_runtime.h>
#include <hip/hip_fp16.h>
#include <math.h>

#define N_NODES 100000
#define N_EDGES 1600000
#define IN_DIM  128
#define HID     64
#define NCOMM   32
#define NB        391   // ceil(100000/256) coarse buckets
#define BSHIFT    8     // 256 nodes per bucket
#define EPB       4096  // edges per block in binning kernels
#define NBIN_BLK  391   // ceil(1600000/4096)

typedef _Float16 f16x8 __attribute__((ext_vector_type(8)));
typedef float    f32x4 __attribute__((ext_vector_type(4)));

// ---------- edge dtype detection (int64 vs int32), parallel, deterministic ----------
__global__ void k_detect(const unsigned int* __restrict__ e, int* __restrict__ flag) {
  int lane = threadIdx.x;  // 64 lanes
  unsigned v = 0;
  #pragma unroll
  for (int i = 0; i < 4; ++i) v |= e[2 * (lane * 4 + i) + 1];
  unsigned long long nz = __ballot(v != 0u);
  if (lane == 0) *flag = (nz == 0ull) ? 1 : 0;  // 1 => int64 layout
}

__device__ __forceinline__ int load_idx(const int* e32, long long pos, int is64) {
  if (is64) return (int)(((const long long*)e32)[pos]);
  return e32[pos];
}

// ---------- coarse bucket histogram (LDS counters, few global atomics) ----------
__global__ __launch_bounds__(256) void k_bhist(const int* __restrict__ e, int* __restrict__ bcnt,
                                               const int* __restrict__ flag) {
  __shared__ int cnt[NB];
  for (int i = threadIdx.x; i < NB; i += 256) cnt[i] = 0;
  __syncthreads();
  int is64 = *flag;
  long long base = (long long)blockIdx.x * EPB;
  #pragma unroll
  for (int j = 0; j < EPB / 256; ++j) {
    long long eid = base + j * 256 + threadIdx.x;
    if (eid < N_EDGES) {
      int c = load_idx(e, (long long)N_EDGES + eid, is64);
      atomicAdd(&cnt[c >> BSHIFT], 1);
    }
  }
  __syncthreads();
  for (int b = threadIdx.x; b < NB; b += 256)
    if (cnt[b]) atomicAdd(&bcnt[b], cnt[b]);
}

// ---------- scan coarse buckets -> bptr, bcur ----------
__global__ __launch_bounds__(512) void k_bscan(const int* __restrict__ bcnt, int* __restrict__ bptr,
                                               int* __restrict__ bcur) {
  __shared__ int sm[512];
  int t = threadIdx.x;
  int v = (t < NB) ? bcnt[t] : 0;
  sm[t] = v;
  __syncthreads();
  for (int off = 1; off < 512; off <<= 1) {
    int u = (t >= off) ? sm[t - off] : 0;
    __syncthreads();
    sm[t] += u;
    __syncthreads();
  }
  if (t < NB) {
    int ex = sm[t] - v;
    bptr[t] = ex;
    bcur[t] = ex;
  }
  if (t == 0) bptr[NB] = N_EDGES;
}

// ---------- bin edges into coarse buckets as packed (r,c) ----------
__global__ __launch_bounds__(256) void k_bin(const int* __restrict__ e, int* __restrict__ bcur,
                                             uint2* __restrict__ ebuf, const int* __restrict__ flag) {
  __shared__ int cnt[NB];
  __shared__ int base[NB];
  for (int i = threadIdx.x; i < NB; i += 256) cnt[i] = 0;
  __syncthreads();
  int is64 = *flag;
  long long eb = (long long)blockIdx.x * EPB;
  int rr[EPB / 256], cc[EPB / 256], lr[EPB / 256];
  #pragma unroll
  for (int j = 0; j < EPB / 256; ++j) {
    long long eid = eb + j * 256 + threadIdx.x;
    if (eid < N_EDGES) {
      rr[j] = load_idx(e, eid, is64);
      cc[j] = load_idx(e, (long long)N_EDGES + eid, is64);
      lr[j] = atomicAdd(&cnt[cc[j] >> BSHIFT], 1);
    }
  }
  __syncthreads();
  for (int b = threadIdx.x; b < NB; b += 256)
    base[b] = cnt[b] ? atomicAdd(&bcur[b], cnt[b]) : 0;
  __syncthreads();
  #pragma unroll
  for (int j = 0; j < EPB / 256; ++j) {
    long long eid = eb + j * 256 + threadIdx.x;
    if (eid < N_EDGES) {
      int pos = base[cc[j] >> BSHIFT] + lr[j];
      ebuf[pos] = make_uint2((unsigned)rr[j], (unsigned)cc[j]);
    }
  }
}

// ---------- per-bucket degree histogram + dinv + ptr (fused local scan; base = bptr[b]) ----------
__global__ __launch_bounds__(256) void k_deg(const uint2* __restrict__ ebuf, const int* __restrict__ bptr,
                                             float* __restrict__ dinv, int* __restrict__ ptr) {
  __shared__ int cnt[256];
  __shared__ int scn[256];
  int t = threadIdx.x;
  int b = blockIdx.x;
  int c0 = b << BSHIFT;
  cnt[t] = 0;
  __syncthreads();
  int s = bptr[b], epos = bptr[b + 1];
  for (int i = s + t; i < epos; i += 256)
    atomicAdd(&cnt[(int)ebuf[i].y - c0], 1);
  __syncthreads();
  int d = cnt[t];
  scn[t] = d;
  __syncthreads();
  for (int off = 1; off < 256; off <<= 1) {
    int u = (t >= off) ? scn[t - off] : 0;
    __syncthreads();
    scn[t] += u;
    __syncthreads();
  }
  int node = c0 + t;
  if (node < N_NODES) {
    dinv[node] = rsqrtf((float)d + 1.0f);   // +1 = self loop; always > 0
    ptr[node] = bptr[b] + scn[t] - d;       // global exclusive offset
  }
  if (b == NB - 1 && t == 0) ptr[N_NODES] = N_EDGES;
}

// ---------- fine sort within bucket: LDS cursors, write packed (r, w=dinv[r]*dinv[c]) ----------
__global__ __launch_bounds__(1024) void k_fsort(const uint2* __restrict__ ebuf, const int* __restrict__ bptr,
                                                const int* __restrict__ ptr, const float* __restrict__ dinv,
                                                uint2* __restrict__ pk) {
  __shared__ int cur[256];
  int b = blockIdx.x;
  int c0 = b << BSHIFT;
  if (threadIdx.x < 256) {
    int node = c0 + threadIdx.x;
    cur[threadIdx.x] = (node < N_NODES) ? ptr[node] : 0;
  }
  __syncthreads();
  int s = bptr[b], epos = bptr[b + 1];
  for (int i = s + (int)threadIdx.x; i < epos; i += 1024) {
    uint2 ed = ebuf[i];
    int r = (int)ed.x, c = (int)ed.y;
    float w = dinv[r] * dinv[c];
    int pos = atomicAdd(&cur[c - c0], 1);
    pk[pos] = make_uint2((unsigned)r, __float_as_uint(w));
  }
}

// ---------- MFMA GEMM: Y[n,M] = X[n,K] @ W[K,M], fp16 inputs, fp32 accumulate ----------
// 256 threads = 4 waves; each wave: 32 rows x M cols via 16x16x32 MFMA tiles.
// A-fragments: direct global->register (lane l: row base+(l&15), k-chunk 8*(l>>4)).
// W^T staged in LDS fp16 with XOR swizzle ((col&7)<<4) to kill stride bank conflicts.
// C/D layout (m89-verified): col = lane&15, row = (lane>>4)*4 + reg.
template<int K, int M, bool FINAL, bool INH>
__global__ __launch_bounds__(256) void k_mfma(const void* __restrict__ X, const float* __restrict__ W,
                                              void* __restrict__ Y, const float* __restrict__ bias) {
  constexpr int NN = M / 16;   // n-tiles per wave (4 or 2)
  constexpr int KS = K / 32;   // k-steps (4 or 2)
  __shared__ char smem[M * K * 2];  // W^T fp16, swizzled

  const int tid = threadIdx.x;
  // stage W^T: read W[K][M] row-major fp32, write Wt[m][k] fp16 at swizzled offset
  for (int i = tid; i < K * M / 4; i += 256) {
    int k  = i / (M / 4);
    int mf = (i % (M / 4)) * 4;
    float4 wv = *(const float4*)(W + (size_t)k * M + mf);
    float wa[4] = {wv.x, wv.y, wv.z, wv.w};
    #pragma unroll
    for (int c = 0; c < 4; ++c) {
      int m = mf + c;
      int byte_off = m * (2 * K) + ((((k >> 3) << 4)) ^ ((m & 7) << 4)) + (k & 7) * 2;
      *(_Float16*)(smem + byte_off) = (_Float16)wa[c];
    }
  }
  __syncthreads();

  const int lane = tid & 63;
  const int wv_  = tid >> 6;
  const int rowbase = blockIdx.x * 128 + wv_ * 32;
  const int lr = lane & 15;
  const int kg = lane >> 4;           // 0..3: k-chunk / C-row group
  const int r0 = rowbase + lr;        // A rows for m-tile 0
  const int r1 = r0 + 16;             // m-tile 1
  const int rc0 = (r0 < N_NODES) ? r0 : (N_NODES - 1);
  const int rc1 = (r1 < N_NODES) ? r1 : (N_NODES - 1);

  f32x4 acc[2][NN] = {};

  #pragma unroll
  for (int ks = 0; ks < KS; ++ks) {
    const int k0 = ks * 32 + kg * 8;
    f16x8 a0, a1;
    if constexpr (!INH) {  // fp32 source (x): load 32 B, convert in-register
      const float* xr = (const float*)X;
      float4 u0 = *(const float4*)(xr + (size_t)rc0 * K + k0);
      float4 u1 = *(const float4*)(xr + (size_t)rc0 * K + k0 + 4);
      float4 u2 = *(const float4*)(xr + (size_t)rc1 * K + k0);
      float4 u3 = *(const float4*)(xr + (size_t)rc1 * K + k0 + 4);
      a0[0] = (_Float16)u0.x; a0[1] = (_Float16)u0.y; a0[2] = (_Float16)u0.z; a0[3] = (_Float16)u0.w;
      a0[4] = (_Float16)u1.x; a0[5] = (_Float16)u1.y; a0[6] = (_Float16)u1.z; a0[7] = (_Float16)u1.w;
      a1[0] = (_Float16)u2.x; a1[1] = (_Float16)u2.y; a1[2] = (_Float16)u2.z; a1[3] = (_Float16)u2.w;
      a1[4] = (_Float16)u3.x; a1[5] = (_Float16)u3.y; a1[6] = (_Float16)u3.z; a1[7] = (_Float16)u3.w;
    } else {               // fp16 source: 16 B direct
      const char* xb = (const char*)X;
      a0 = *(const f16x8*)(xb + (size_t)rc0 * (2 * K) + k0 * 2);
      a1 = *(const f16x8*)(xb + (size_t)rc1 * (2 * K) + k0 * 2);
    }
    const int slot = (k0 >> 3) << 4;
    #pragma unroll
    for (int n = 0; n < NN; ++n) {
      const int col = n * 16 + lr;
      f16x8 b = *(const f16x8*)(smem + col * (2 * K) + (slot ^ ((col & 7) << 4)));
      acc[0][n] = __builtin_amdgcn_mfma_f32_16x16x32_f16(a0, b, acc[0][n], 0, 0, 0);
      acc[1][n] = __builtin_amdgcn_mfma_f32_16x16x32_f16(a1, b, acc[1][n], 0, 0, 0);
    }
  }

  #pragma unroll
  for (int m2 = 0; m2 < 2; ++m2) {
    #pragma unroll
    for (int n = 0; n < NN; ++n) {
      const int col = n * 16 + lr;
      #pragma unroll
      for (int r = 0; r < 4; ++r) {
        const int row = rowbase + m2 * 16 + kg * 4 + r;
        if (row < N_NODES) {
          float v = acc[m2][n][r];
          if constexpr (FINAL) {
            v += bias[col];
            v = 1.f / (1.f + __expf(-v));
            ((float*)Y)[(size_t)row * M + col] = v;
          } else {
            ((__half*)Y)[(size_t)row * M + col] = __float2half(v);
          }
        }
      }
    }
  }
}

// ---------- pull aggregation, fp16 in/out, 8 edges per wave, unroll 2 ----------
// O[c] = relu( sum_in H[r]*w_e + H[c]*dinv[c]^2 + b ),  w_e precomputed in pk
__device__ __forceinline__ void acc8(float* acc, uint4 h, float w) {
  __half2 p0 = *(__half2*)&h.x;
  __half2 p1 = *(__half2*)&h.y;
  __half2 p2 = *(__half2*)&h.z;
  __half2 p3 = *(__half2*)&h.w;
  float2 f0 = __half22float2(p0);
  float2 f1 = __half22float2(p1);
  float2 f2 = __half22float2(p2);
  float2 f3 = __half22float2(p3);
  acc[0] += f0.x * w; acc[1] += f0.y * w;
  acc[2] += f1.x * w; acc[3] += f1.y * w;
  acc[4] += f2.x * w; acc[5] += f2.y * w;
  acc[6] += f3.x * w; acc[7] += f3.y * w;
}

__global__ __launch_bounds__(256) void k_agg(const __half* __restrict__ H, __half* __restrict__ O,
                                             const int* __restrict__ ptr, const uint2* __restrict__ pk,
                                             const float* __restrict__ dinv, const float* __restrict__ bias) {
  int wid  = (blockIdx.x * 256 + threadIdx.x) >> 6;  // node (one wave per node)
  int lane = threadIdx.x & 63;
  if (wid >= N_NODES) return;
  const int q  = lane >> 3;   // edge slot 0..7
  const int fl = lane & 7;    // feature octet: features 8*fl .. 8*fl+7 (16 B)
  const char* Hb = (const char*)H;
  int s = ptr[wid], e = ptr[wid + 1];
  float acc[8] = {0.f, 0.f, 0.f, 0.f, 0.f, 0.f, 0.f, 0.f};
  for (int j = s; j < e; j += 16) {
    int i0 = j + q;
    int i1 = j + 8 + q;
    bool v0 = i0 < e;
    bool v1 = i1 < e;
    uint2 e0 = pk[v0 ? i0 : j];   // j < e inside loop, always valid
    uint2 e1 = pk[v1 ? i1 : j];
    float w0 = v0 ? __uint_as_float(e0.y) : 0.f;
    float w1 = v1 ? __uint_as_float(e1.y) : 0.f;
    uint4 h0 = *(const uint4*)(Hb + (size_t)e0.x * (HID * 2) + fl * 16);
    uint4 h1 = *(const uint4*)(Hb + (size_t)e1.x * (HID * 2) + fl * 16);
    acc8(acc, h0, w0);
    acc8(acc, h1, w1);
  }
  if (q == 0) {  // self loop, counted once
    float di = dinv[wid];
    uint4 hb = *(const uint4*)(Hb + (size_t)wid * (HID * 2) + fl * 16);
    acc8(acc, hb, di * di);
  }
  // merge the 8 edge slots
  #pragma unroll
  for (int m = 8; m < 64; m <<= 1) {
    #pragma unroll
    for (int i = 0; i < 8; ++i) acc[i] += __shfl_xor(acc[i], m, 64);
  }
  if (lane < 8) {
    float4 ba = ((const float4*)bias)[2 * fl + 0];
    float4 bb = ((const float4*)bias)[2 * fl + 1];
    __half2 o0 = __floats2half2_rn(fmaxf(acc[0] + ba.x, 0.f), fmaxf(acc[1] + ba.y, 0.f));
    __half2 o1 = __floats2half2_rn(fmaxf(acc[2] + ba.z, 0.f), fmaxf(acc[3] + ba.w, 0.f));
    __half2 o2 = __floats2half2_rn(fmaxf(acc[4] + bb.x, 0.f), fmaxf(acc[5] + bb.y, 0.f));
    __half2 o3 = __floats2half2_rn(fmaxf(acc[6] + bb.z, 0.f), fmaxf(acc[7] + bb.w, 0.f));
    uint4 pv;
    pv.x = *(unsigned*)&o0;
    pv.y = *(unsigned*)&o1;
    pv.z = *(unsigned*)&o2;
    pv.w = *(unsigned*)&o3;
    *(uint4*)((char*)O + (size_t)wid * (HID * 2) + fl * 16) = pv;
  }
}

extern "C" void kernel_launch(void* const* d_in, const int* in_sizes, int n_in,
                              void* d_out, int out_size, void* d_ws, size_t ws_size,
                              hipStream_t stream) {
  const float* x   = (const float*)d_in[0];
  const int*   e   = (const int*)d_in[1];
  const float* W1  = (const float*)d_in[2];
  const float* b1  = (const float*)d_in[3];
  const float* W2  = (const float*)d_in[4];
  const float* b2  = (const float*)d_in[5];
  const float* Wfc = (const float*)d_in[6];
  const float* bfc = (const float*)d_in[7];
  float* out = (float*)d_out;

  // workspace layout (bytes) — total < 40 MB
  char* ws = (char*)d_ws;
  __half* hbuf = (__half*)(ws);             // N*64 fp16 = 12,800,000 (gather rows)
  uint2*  ebuf = (uint2*) (ws);             // E uint2 (ALIASED on hbuf; dead before gemm1)
  uint2*  pk   = (uint2*) (ws + 12800000);  // E uint2 packed (r, w) = 12,800,000
  __half* abuf = (__half*)(ws + 25600000);  // N*64 fp16 = 12,800,000 (agg outputs)
  float*  dinv = (float*) (ws + 38400000);  // N f32
  int*    ptr  = (int*)   (ws + 38800000);  // (N+1) i32
  int*    flag = (int*)   (ws + 39200064);  // 1 i32
  int*    bcnt = (int*)   (ws + 39200128);  // NB i32
  int*    bptr = (int*)   (ws + 39201728);  // NB+1 i32
  int*    bcur = (int*)   (ws + 39203392);  // NB i32

  hipMemsetAsync(bcnt, 0, NB * sizeof(int), stream);
  k_detect<<<1, 64, 0, stream>>>((const unsigned int*)e, flag);
  k_bhist<<<NBIN_BLK, 256, 0, stream>>>(e, bcnt, flag);
  k_bscan<<<1, 512, 0, stream>>>(bcnt, bptr, bcur);
  k_bin<<<NBIN_BLK, 256, 0, stream>>>(e, bcur, ebuf, flag);
  k_deg<<<NB, 256, 0, stream>>>(ebuf, bptr, dinv, ptr);
  k_fsort<<<NB, 1024, 0, stream>>>(ebuf, bptr, ptr, dinv, pk);

  const int gBlocks = (N_NODES + 127) / 128;
  k_mfma<IN_DIM, HID, false, false><<<gBlocks, 256, 0, stream>>>(x, W1, hbuf, nullptr);
  k_agg<<<N_NODES * 64 / 256, 256, 0, stream>>>(hbuf, abuf, ptr, pk, dinv, b1);
  k_mfma<HID, HID, false, true><<<gBlocks, 256, 0, stream>>>(abuf, W2, hbuf, nullptr);
  k_agg<<<N_NODES * 64 / 256, 256, 0, stream>>>(hbuf, abuf, ptr, pk, dinv, b2);
  k_mfma<HID, NCOMM, true, true><<<gBlocks, 256, 0, stream>>>(abuf, Wfc, out, bfc);
}

// Round 8
// 203.769 us; speedup vs baseline: 5.2857x; 1.0052x over previous
//
#include <hip/hip_runtime.h>
#include <hip/hip_fp16.h>
#include <math.h>

#define N_NODES 100000
#define N_EDGES 1600000
#define IN_DIM  128
#define HID     64
#define NCOMM   32
#define NB        391   // ceil(100000/256) coarse buckets
#define BSHIFT    8     // 256 nodes per bucket
#define EPB       4096  // edges per block in binning kernels
#define NBIN_BLK  391   // ceil(1600000/4096)

typedef _Float16 f16x8 __attribute__((ext_vector_type(8)));
typedef float    f32x4 __attribute__((ext_vector_type(4)));

// ---------- edge dtype detection (int64 vs int32), parallel, deterministic ----------
__global__ void k_detect(const unsigned int* __restrict__ e, int* __restrict__ flag) {
  int lane = threadIdx.x;  // 64 lanes
  unsigned v = 0;
  #pragma unroll
  for (int i = 0; i < 4; ++i) v |= e[2 * (lane * 4 + i) + 1];
  unsigned long long nz = __ballot(v != 0u);
  if (lane == 0) *flag = (nz == 0ull) ? 1 : 0;  // 1 => int64 layout
}

__device__ __forceinline__ int load_idx(const int* e32, long long pos, int is64) {
  if (is64) return (int)(((const long long*)e32)[pos]);
  return e32[pos];
}

// ---------- coarse bucket histogram (LDS counters, few global atomics) ----------
__global__ __launch_bounds__(256) void k_bhist(const int* __restrict__ e, int* __restrict__ bcnt,
                                               const int* __restrict__ flag) {
  __shared__ int cnt[NB];
  for (int i = threadIdx.x; i < NB; i += 256) cnt[i] = 0;
  __syncthreads();
  int is64 = *flag;
  long long base = (long long)blockIdx.x * EPB;
  #pragma unroll
  for (int j = 0; j < EPB / 256; ++j) {
    long long eid = base + j * 256 + threadIdx.x;
    if (eid < N_EDGES) {
      int c = load_idx(e, (long long)N_EDGES + eid, is64);
      atomicAdd(&cnt[c >> BSHIFT], 1);
    }
  }
  __syncthreads();
  for (int b = threadIdx.x; b < NB; b += 256)
    if (cnt[b]) atomicAdd(&bcnt[b], cnt[b]);
}

// ---------- scan coarse buckets -> bptr, bcur ----------
__global__ __launch_bounds__(512) void k_bscan(const int* __restrict__ bcnt, int* __restrict__ bptr,
                                               int* __restrict__ bcur) {
  __shared__ int sm[512];
  int t = threadIdx.x;
  int v = (t < NB) ? bcnt[t] : 0;
  sm[t] = v;
  __syncthreads();
  for (int off = 1; off < 512; off <<= 1) {
    int u = (t >= off) ? sm[t - off] : 0;
    __syncthreads();
    sm[t] += u;
    __syncthreads();
  }
  if (t < NB) {
    int ex = sm[t] - v;
    bptr[t] = ex;
    bcur[t] = ex;
  }
  if (t == 0) bptr[NB] = N_EDGES;
}

// ---------- bin edges into coarse buckets, packed: bits[0:17)=r, bits[17:25)=c&255 ----------
__global__ __launch_bounds__(256) void k_bin(const int* __restrict__ e, int* __restrict__ bcur,
                                             unsigned* __restrict__ ebuf, const int* __restrict__ flag) {
  __shared__ int cnt[NB];
  __shared__ int base[NB];
  for (int i = threadIdx.x; i < NB; i += 256) cnt[i] = 0;
  __syncthreads();
  int is64 = *flag;
  long long eb = (long long)blockIdx.x * EPB;
  int rr[EPB / 256], cc[EPB / 256], lr[EPB / 256];
  #pragma unroll
  for (int j = 0; j < EPB / 256; ++j) {
    long long eid = eb + j * 256 + threadIdx.x;
    if (eid < N_EDGES) {
      rr[j] = load_idx(e, eid, is64);
      cc[j] = load_idx(e, (long long)N_EDGES + eid, is64);
      lr[j] = atomicAdd(&cnt[cc[j] >> BSHIFT], 1);
    }
  }
  __syncthreads();
  for (int b = threadIdx.x; b < NB; b += 256)
    base[b] = cnt[b] ? atomicAdd(&bcur[b], cnt[b]) : 0;
  __syncthreads();
  #pragma unroll
  for (int j = 0; j < EPB / 256; ++j) {
    long long eid = eb + j * 256 + threadIdx.x;
    if (eid < N_EDGES) {
      int pos = base[cc[j] >> BSHIFT] + lr[j];
      ebuf[pos] = ((unsigned)(cc[j] & 255) << 17) | (unsigned)rr[j];
    }
  }
}

// ---------- fused: per-bucket degree histogram + dinv + ptr + in-bucket counting sort ----------
__global__ __launch_bounds__(256) void k_degsort(const unsigned* __restrict__ ebuf, const int* __restrict__ bptr,
                                                 float* __restrict__ dinv, int* __restrict__ ptr,
                                                 int* __restrict__ srow) {
  __shared__ int cnt[256];
  __shared__ int scn[256];
  __shared__ int cur[256];
  int t = threadIdx.x;
  int b = blockIdx.x;
  int c0 = b << BSHIFT;
  cnt[t] = 0;
  __syncthreads();
  int s = bptr[b], epos = bptr[b + 1];
  for (int i = s + t; i < epos; i += 256)
    atomicAdd(&cnt[ebuf[i] >> 17], 1);
  __syncthreads();
  int d = cnt[t];
  scn[t] = d;
  __syncthreads();
  for (int off = 1; off < 256; off <<= 1) {
    int u = (t >= off) ? scn[t - off] : 0;
    __syncthreads();
    scn[t] += u;
    __syncthreads();
  }
  int myptr = s + scn[t] - d;   // global exclusive offset for node c0+t
  int node = c0 + t;
  if (node < N_NODES) {
    dinv[node] = rsqrtf((float)d + 1.0f);   // +1 = self loop; always > 0
    ptr[node] = myptr;
  }
  cur[t] = myptr;
  __syncthreads();
  for (int i = s + t; i < epos; i += 256) {
    unsigned w = ebuf[i];
    int pos = atomicAdd(&cur[w >> 17], 1);
    srow[pos] = (int)(w & 0x1FFFFu);
  }
  if (b == NB - 1 && t == 0) ptr[N_NODES] = N_EDGES;
}

// ---------- MFMA GEMM: Y[n,M] = X[n,K] @ W[K,M], fp16 in, fp32 acc ----------
// Non-FINAL: output row scaled by dinv[row] (folds the source-side GCN norm into storage).
// 256 threads = 4 waves; wave: 32 rows x M cols via 16x16x32 MFMA tiles.
// C/D layout (m89-verified): col = lane&15, row = (lane>>4)*4 + reg.
template<int K, int M, bool FINAL, bool INH>
__global__ __launch_bounds__(256) void k_mfma(const void* __restrict__ X, const float* __restrict__ W,
                                              void* __restrict__ Y, const float* __restrict__ bias,
                                              const float* __restrict__ dscale) {
  constexpr int NN = M / 16;   // n-tiles per wave
  constexpr int KS = K / 32;   // k-steps
  __shared__ char smem[M * K * 2];  // W^T fp16, swizzled

  const int tid = threadIdx.x;
  for (int i = tid; i < K * M / 4; i += 256) {
    int k  = i / (M / 4);
    int mf = (i % (M / 4)) * 4;
    float4 wv = *(const float4*)(W + (size_t)k * M + mf);
    float wa[4] = {wv.x, wv.y, wv.z, wv.w};
    #pragma unroll
    for (int c = 0; c < 4; ++c) {
      int m = mf + c;
      int byte_off = m * (2 * K) + ((((k >> 3) << 4)) ^ ((m & 7) << 4)) + (k & 7) * 2;
      *(_Float16*)(smem + byte_off) = (_Float16)wa[c];
    }
  }
  __syncthreads();

  const int lane = tid & 63;
  const int wv_  = tid >> 6;
  const int rowbase = blockIdx.x * 128 + wv_ * 32;
  const int lr = lane & 15;
  const int kg = lane >> 4;
  const int r0 = rowbase + lr;
  const int r1 = r0 + 16;
  const int rc0 = (r0 < N_NODES) ? r0 : (N_NODES - 1);
  const int rc1 = (r1 < N_NODES) ? r1 : (N_NODES - 1);

  f32x4 acc[2][NN] = {};

  #pragma unroll
  for (int ks = 0; ks < KS; ++ks) {
    const int k0 = ks * 32 + kg * 8;
    f16x8 a0, a1;
    if constexpr (!INH) {
      const float* xr = (const float*)X;
      float4 u0 = *(const float4*)(xr + (size_t)rc0 * K + k0);
      float4 u1 = *(const float4*)(xr + (size_t)rc0 * K + k0 + 4);
      float4 u2 = *(const float4*)(xr + (size_t)rc1 * K + k0);
      float4 u3 = *(const float4*)(xr + (size_t)rc1 * K + k0 + 4);
      a0[0] = (_Float16)u0.x; a0[1] = (_Float16)u0.y; a0[2] = (_Float16)u0.z; a0[3] = (_Float16)u0.w;
      a0[4] = (_Float16)u1.x; a0[5] = (_Float16)u1.y; a0[6] = (_Float16)u1.z; a0[7] = (_Float16)u1.w;
      a1[0] = (_Float16)u2.x; a1[1] = (_Float16)u2.y; a1[2] = (_Float16)u2.z; a1[3] = (_Float16)u2.w;
      a1[4] = (_Float16)u3.x; a1[5] = (_Float16)u3.y; a1[6] = (_Float16)u3.z; a1[7] = (_Float16)u3.w;
    } else {
      const char* xb = (const char*)X;
      a0 = *(const f16x8*)(xb + (size_t)rc0 * (2 * K) + k0 * 2);
      a1 = *(const f16x8*)(xb + (size_t)rc1 * (2 * K) + k0 * 2);
    }
    const int slot = (k0 >> 3) << 4;
    #pragma unroll
    for (int n = 0; n < NN; ++n) {
      const int col = n * 16 + lr;
      f16x8 b = *(const f16x8*)(smem + col * (2 * K) + (slot ^ ((col & 7) << 4)));
      acc[0][n] = __builtin_amdgcn_mfma_f32_16x16x32_f16(a0, b, acc[0][n], 0, 0, 0);
      acc[1][n] = __builtin_amdgcn_mfma_f32_16x16x32_f16(a1, b, acc[1][n], 0, 0, 0);
    }
  }

  #pragma unroll
  for (int m2 = 0; m2 < 2; ++m2) {
    #pragma unroll
    for (int r = 0; r < 4; ++r) {
      const int row = rowbase + m2 * 16 + kg * 4 + r;
      if (row < N_NODES) {
        float ds = FINAL ? 0.f : dscale[row];
        #pragma unroll
        for (int n = 0; n < NN; ++n) {
          const int col = n * 16 + lr;
          float v = acc[m2][n][r];
          if constexpr (FINAL) {
            v += bias[col];
            v = 1.f / (1.f + __expf(-v));
            ((float*)Y)[(size_t)row * M + col] = v;
          } else {
            ((__half*)Y)[(size_t)row * M + col] = __float2half(v * ds);
          }
        }
      }
    }
  }
}

// ---------- pull aggregation: O[c] = relu( dinv[c]*( sum_in H[r] + H[c] ) + b ) ----------
// H rows pre-scaled by dinv[r] in the GEMM epilogue; row N_NODES is a zero row for tail slots.
__device__ __forceinline__ void addrow(float* acc, uint4 h) {
  __half2 p0 = *(__half2*)&h.x;
  __half2 p1 = *(__half2*)&h.y;
  __half2 p2 = *(__half2*)&h.z;
  __half2 p3 = *(__half2*)&h.w;
  float2 f0 = __half22float2(p0);
  float2 f1 = __half22float2(p1);
  float2 f2 = __half22float2(p2);
  float2 f3 = __half22float2(p3);
  acc[0] += f0.x; acc[1] += f0.y;
  acc[2] += f1.x; acc[3] += f1.y;
  acc[4] += f2.x; acc[5] += f2.y;
  acc[6] += f3.x; acc[7] += f3.y;
}

__global__ __launch_bounds__(256) void k_agg(const __half* __restrict__ H, __half* __restrict__ O,
                                             const int* __restrict__ ptr, const int* __restrict__ srow,
                                             const float* __restrict__ dinv, const float* __restrict__ bias) {
  int wid  = (blockIdx.x * 256 + threadIdx.x) >> 6;  // node (one wave per node)
  int lane = threadIdx.x & 63;
  if (wid >= N_NODES) return;
  const int q  = lane >> 3;   // edge slot 0..7
  const int fl = lane & 7;    // feature octet: features 8*fl .. 8*fl+7 (16 B)
  const char* Hb = (const char*)H;
  int s = ptr[wid], e = ptr[wid + 1];
  float acc[8] = {0.f, 0.f, 0.f, 0.f, 0.f, 0.f, 0.f, 0.f};
  for (int j = s; j < e; j += 16) {
    int i0 = j + q;
    int i1 = j + 8 + q;
    int r0 = srow[i0];               // srow padded by 16 ints; invalid -> zero row
    int r1 = srow[i1];
    r0 = (i0 < e) ? r0 : N_NODES;
    r1 = (i1 < e) ? r1 : N_NODES;
    uint4 h0 = *(const uint4*)(Hb + (size_t)((unsigned)r0 * 128u + (unsigned)fl * 16u));
    uint4 h1 = *(const uint4*)(Hb + (size_t)((unsigned)r1 * 128u + (unsigned)fl * 16u));
    addrow(acc, h0);
    addrow(acc, h1);
  }
  if (q == 0) {  // self loop (H[c] pre-scaled by dinv[c])
    uint4 hb = *(const uint4*)(Hb + (size_t)((unsigned)wid * 128u + (unsigned)fl * 16u));
    addrow(acc, hb);
  }
  // merge the 8 edge slots
  #pragma unroll
  for (int m = 8; m < 64; m <<= 1) {
    #pragma unroll
    for (int i = 0; i < 8; ++i) acc[i] += __shfl_xor(acc[i], m, 64);
  }
  if (lane < 8) {
    float di = dinv[wid];
    float4 ba = ((const float4*)bias)[2 * fl + 0];
    float4 bb = ((const float4*)bias)[2 * fl + 1];
    __half2 o0 = __floats2half2_rn(fmaxf(acc[0] * di + ba.x, 0.f), fmaxf(acc[1] * di + ba.y, 0.f));
    __half2 o1 = __floats2half2_rn(fmaxf(acc[2] * di + ba.z, 0.f), fmaxf(acc[3] * di + ba.w, 0.f));
    __half2 o2 = __floats2half2_rn(fmaxf(acc[4] * di + bb.x, 0.f), fmaxf(acc[5] * di + bb.y, 0.f));
    __half2 o3 = __floats2half2_rn(fmaxf(acc[6] * di + bb.z, 0.f), fmaxf(acc[7] * di + bb.w, 0.f));
    uint4 pv;
    pv.x = *(unsigned*)&o0;
    pv.y = *(unsigned*)&o1;
    pv.z = *(unsigned*)&o2;
    pv.w = *(unsigned*)&o3;
    *(uint4*)((char*)O + (size_t)wid * (HID * 2) + fl * 16) = pv;
  }
}

extern "C" void kernel_launch(void* const* d_in, const int* in_sizes, int n_in,
                              void* d_out, int out_size, void* d_ws, size_t ws_size,
                              hipStream_t stream) {
  const float* x   = (const float*)d_in[0];
  const int*   e   = (const int*)d_in[1];
  const float* W1  = (const float*)d_in[2];
  const float* b1  = (const float*)d_in[3];
  const float* W2  = (const float*)d_in[4];
  const float* b2  = (const float*)d_in[5];
  const float* Wfc = (const float*)d_in[6];
  const float* bfc = (const float*)d_in[7];
  float* out = (float*)d_out;

  // workspace layout (bytes) — total ~33 MB
  char* ws = (char*)d_ws;
  __half*   hbuf = (__half*)  (ws);             // (N+1)*64 fp16 = 12,800,128 (row N = zero row)
  unsigned* ebuf = (unsigned*)(ws);             // E uint = 6,400,000 (ALIASED; dead before gemm1)
  int*      srow = (int*)     (ws + 12800256);  // E i32 = 6,400,000 (+64 pad for tail reads)
  __half*   abuf = (__half*)  (ws + 19200320);  // N*64 fp16 = 12,800,000 (agg outputs)
  float*    dinv = (float*)   (ws + 32000320);  // N f32
  int*      ptr  = (int*)     (ws + 32400320);  // (N+1) i32
  int*      flag = (int*)     (ws + 32800384);  // 1 i32
  int*      bcnt = (int*)     (ws + 32800448);  // NB i32
  int*      bptr = (int*)     (ws + 32802048);  // NB+1 i32
  int*      bcur = (int*)     (ws + 32803712);  // NB i32

  hipMemsetAsync(bcnt, 0, NB * sizeof(int), stream);
  hipMemsetAsync(ws + (size_t)N_NODES * 128, 0, 128, stream);  // zero row (outside ebuf's 6.4MB)
  k_detect<<<1, 64, 0, stream>>>((const unsigned int*)e, flag);
  k_bhist<<<NBIN_BLK, 256, 0, stream>>>(e, bcnt, flag);
  k_bscan<<<1, 512, 0, stream>>>(bcnt, bptr, bcur);
  k_bin<<<NBIN_BLK, 256, 0, stream>>>(e, bcur, ebuf, flag);
  k_degsort<<<NB, 256, 0, stream>>>(ebuf, bptr, dinv, ptr, srow);

  const int gBlocks = (N_NODES + 127) / 128;
  k_mfma<IN_DIM, HID, false, false><<<gBlocks, 256, 0, stream>>>(x, W1, hbuf, nullptr, dinv);
  k_agg<<<N_NODES * 64 / 256, 256, 0, stream>>>(hbuf, abuf, ptr, srow, dinv, b1);
  k_mfma<HID, HID, false, true><<<gBlocks, 256, 0, stream>>>(abuf, W2, hbuf, nullptr, dinv);
  k_agg<<<N_NODES * 64 / 256, 256, 0, stream>>>(hbuf, abuf, ptr, srow, dinv, b2);
  k_mfma<HID, NCOMM, true, true><<<gBlocks, 256, 0, stream>>>(abuf, Wfc, out, bfc, nullptr);
}